// Round 6
// baseline (4002.794 us; speedup 1.0000x reference)
//
#include <hip/hip_runtime.h>
#include <hip/hip_bf16.h>

#define N_NODES 50000
#define N_EDGES 800000
#define DIM 128
#define BN_EPS 1e-5f
#define GATHER_BLOCKS (N_NODES / 4)           // 12500, 1 node per wave
#define RED_BLOCKS 125
#define CAP 48                                // padded CSR row capacity (actual max deg ~37)

// ---- CSR build constants (LDS counting-sort binning) ----
#define PART_SHIFT 7
#define PART_SIZE 128
#define NPARTS ((N_NODES + PART_SIZE - 1) / PART_SIZE)   // 391
#define QSTRIDE 32                                       // qcnt pad: 1 counter / 128B line
#define BIN_EPB 4096                                     // edges per binning block
#define BIN_BLOCKS ((N_EDGES + BIN_EPB - 1) / BIN_EPB)   // 196
#define QCAP2 2560                                       // per-part queue cap (mean 2046, +11 sigma)
#define GEMM_BLOCKS (N_NODES / 16)                       // 3125

typedef __attribute__((ext_vector_type(8))) short short8;
typedef __attribute__((ext_vector_type(4))) float float4v;

__device__ __forceinline__ float bf16_bits_to_f32(unsigned short u) {
    union { unsigned int i; float f; } c;
    c.i = ((unsigned int)u) << 16;
    return c.f;
}

__device__ __forceinline__ float bf16_lo(unsigned int u) {
    union { unsigned int i; float f; } c;
    c.i = u << 16;
    return c.f;
}

__device__ __forceinline__ float bf16_hi(unsigned int u) {
    union { unsigned int i; float f; } c;
    c.i = u & 0xFFFF0000u;
    return c.f;
}

__device__ __forceinline__ unsigned short f32_to_bf16_bits(float f) {
    union { float f; unsigned int i; } c;
    c.f = f;
    unsigned int lsb = (c.i >> 16) & 1u;
    c.i += 0x7FFFu + lsb;   // RNE
    return (unsigned short)(c.i >> 16);
}

// ---------------- zero-init helpers (fallback path) ----------------
__global__ __launch_bounds__(256) void zero_int(int* __restrict__ p, int n) {
    int i = blockIdx.x * blockDim.x + threadIdx.x;
    if (i < n) p[i] = 0;
}

// ---------------- prep: dtype sniff (per-block, local) + param convert + zeroing ----------------
// Merges sniff + convert_params + zero_aux into ONE dispatch (round-5 lesson: 14
// serialized dispatches -> launch-gap overhead; cut to 9). Each block recomputes the
// 512-elem dtype sniff locally (1KB, L2-hot) to break the cross-dispatch dependency.
__global__ __launch_bounds__(256) void prep(
    const unsigned short* __restrict__ xu,
    const void* __restrict__ W, const void* __restrict__ b,
    const void* __restrict__ g, const void* __restrict__ be,
    float* __restrict__ modeg, unsigned short* __restrict__ Wt,
    float* __restrict__ pf32,
    int* __restrict__ qcnt, float* __restrict__ stats, int* __restrict__ done) {
    __shared__ int okc;
    if (threadIdx.x == 0) okc = 0;
    __syncthreads();
    int ok = 0;
    for (int i = threadIdx.x; i < 512; i += 256) {
        unsigned e = (xu[i] >> 7) & 0xFFu;
        if (e >= 96u && e <= 159u) ok++;
    }
    atomicAdd(&okc, ok);
    __syncthreads();
    const bool mf32 = okc < 480;   // same rule as old sniff: >=480 -> bf16(0), else f32(1)

    if (blockIdx.x == 0) {
        if (threadIdx.x == 0) { modeg[0] = mf32 ? 1.0f : 0.0f; done[0] = 0; done[1] = 0; }
        for (int i = threadIdx.x; i < NPARTS; i += 256) qcnt[(size_t)i * QSTRIDE] = 0;
        stats[threadIdx.x] = 0.0f;
    }

    int i = blockIdx.x * 256 + threadIdx.x;
    const int NW = 3 * DIM * DIM;  // 49152
    if (i < NW) {
        int l = i >> 14;
        int rem = i & 16383;
        int k = rem >> 7;
        int n = rem & 127;
        unsigned short v = mf32 ? f32_to_bf16_bits(((const float*)W)[i])
                                : ((const unsigned short*)W)[i];
        Wt[(size_t)l * DIM * DIM + (size_t)n * DIM + k] = v;  // transposed
    } else if (i < NW + 3 * 3 * DIM) {
        int p = i - NW;
        int which = p / 384;         // 0=b 1=gamma 2=beta
        int r = p - which * 384;
        const void* srcp = (which == 0) ? b : (which == 1) ? g : be;
        float v = mf32 ? ((const float*)srcp)[r]
                       : bf16_bits_to_f32(((const unsigned short*)srcp)[r]);
        pf32[which * 384 + r] = v;
    }
}

// ---------------- fused: LDS counting-sort binning (196 blocks) || layer-0 GEMM ----------------
__global__ __launch_bounds__(256) void fused_a(
    const int* __restrict__ src, const int* __restrict__ dst,
    int* __restrict__ qcnt, unsigned int* __restrict__ queue,
    const void* __restrict__ x, const unsigned short* __restrict__ Wt,
    const float* __restrict__ mode, unsigned short* __restrict__ A) {
    __shared__ int lcnt[NPARTS];
    __shared__ int loff[NPARTS];   // scan result, then working offsets for pass 2
    __shared__ int adj[NPARTS];    // gbase - pref
    __shared__ unsigned short staged16[BIN_EPB];  // part-sorted local edge ids (8KB)
    __shared__ int sortedN;
    const int bid = blockIdx.x;
    if (bid < BIN_BLOCKS) {
        const int t = threadIdx.x;
        const int blk0 = bid * BIN_EPB;
        const int nval = min(BIN_EPB, N_EDGES - blk0);
        for (int i = t; i < NPARTS; i += 256) lcnt[i] = 0;
        __syncthreads();
        // pass 1: count parts
        for (int li = t; li < nval; li += 256) {
            int d = dst[blk0 + li];
            if ((unsigned)d < (unsigned)N_NODES)
                atomicAdd(&lcnt[d >> PART_SHIFT], 1);
        }
        __syncthreads();
        // wave-0 exclusive prefix scan over NPARTS -> loff (shuffle-based)
        if (t < 64) {
            int base = 0;
            for (int c = 0; c < (NPARTS + 63) / 64; ++c) {
                int idx = c * 64 + t;
                int orig = (idx < NPARTS) ? lcnt[idx] : 0;
                int v = orig;
                #pragma unroll
                for (int o = 1; o < 64; o <<= 1) {
                    int up = __shfl_up(v, o);
                    if (t >= o) v += up;
                }
                if (idx < NPARTS) loff[idx] = base + v - orig;
                base += __shfl(v, 63);
            }
            if (t == 0) sortedN = base;
        }
        __syncthreads();
        // one global reservation per (block, part); adj = gbase - pref
        for (int i = t; i < NPARTS; i += 256) {
            int c = lcnt[i];
            int gb = c ? atomicAdd(&qcnt[(size_t)i * QSTRIDE], c) : 0;
            adj[i] = gb - loff[i];
        }
        __syncthreads();
        // pass 2: LDS sort local edge ids by part (dst re-read, L1-hot window)
        for (int li = t; li < nval; li += 256) {
            int d = dst[blk0 + li];
            if ((unsigned)d < (unsigned)N_NODES) {
                int part = d >> PART_SHIFT;
                int pos = atomicAdd(&loff[part], 1);
                staged16[pos] = (unsigned short)li;
            }
        }
        __syncthreads();
        // output: dense per-part runs; re-derive src/dst (both windows L1-resident)
        const int nOut = sortedN;
        for (int i = t; i < nOut; i += 256) {
            int li = staged16[i];
            int d = dst[blk0 + li];
            int s = src[blk0 + li];
            int part = d >> PART_SHIFT;
            int gp = adj[part] + i;
            if (gp >= 0 && gp < QCAP2)
                queue[(size_t)part * QCAP2 + gp] =
                    (unsigned int)(s & 0xFFFF) |
                    ((unsigned int)(d & (PART_SIZE - 1)) << 16);
        }
        return;
    }
    // ---- layer-0 GEMM (kind 0, unscaled output) ----
    const int wave = threadIdx.x >> 6;
    const int lane = threadIdx.x & 63;
    const int quad = lane >> 4;
    const int nidx = lane & 15;
    const int row0 = (bid - BIN_BLOCKS) * 16;

    short8 afrag[4];
    if (mode[0] > 0.5f) {
        const float* xf = (const float*)x;
        #pragma unroll
        for (int kk = 0; kk < 4; ++kk) {
            const float4v* xr = (const float4v*)(xf + (size_t)(row0 + nidx) * DIM + kk * 32 + quad * 8);
            float4v p0 = xr[0], p1 = xr[1];
            #pragma unroll
            for (int j = 0; j < 4; ++j) {
                afrag[kk][j]     = (short)f32_to_bf16_bits(p0[j]);
                afrag[kk][4 + j] = (short)f32_to_bf16_bits(p1[j]);
            }
        }
    } else {
        const unsigned short* hu = (const unsigned short*)x;
        #pragma unroll
        for (int kk = 0; kk < 4; ++kk)
            afrag[kk] = *(const short8*)(hu + (size_t)(row0 + nidx) * DIM + kk * 32 + quad * 8);
    }

    short8 bfrag[2][4];
    #pragma unroll
    for (int half = 0; half < 2; ++half) {
        int c = wave * 32 + half * 16 + nidx;
        #pragma unroll
        for (int kk = 0; kk < 4; ++kk)
            bfrag[half][kk] = *(const short8*)(Wt + (size_t)c * DIM + kk * 32 + quad * 8);
    }

    float4v acc0 = {0.f, 0.f, 0.f, 0.f};
    float4v acc1 = {0.f, 0.f, 0.f, 0.f};
    #pragma unroll
    for (int kk = 0; kk < 4; ++kk) {
        acc0 = __builtin_amdgcn_mfma_f32_16x16x32_bf16(afrag[kk], bfrag[0][kk], acc0, 0, 0, 0);
        acc1 = __builtin_amdgcn_mfma_f32_16x16x32_bf16(afrag[kk], bfrag[1][kk], acc1, 0, 0, 0);
    }

    #pragma unroll
    for (int r = 0; r < 4; ++r) {
        int row = row0 + quad * 4 + r;
        size_t i0 = (size_t)row * DIM + wave * 32 + nidx;
        A[i0]      = f32_to_bf16_bits(acc0[r]);
        A[i0 + 16] = f32_to_bf16_bits(acc1[r]);
    }
}

// ---------------- phase B: drain per-part queue -> padded CSR, LDS-atomic positions ----------------
__global__ __launch_bounds__(256) void csr_build(
    const int* __restrict__ qcnt, const unsigned int* __restrict__ queue,
    unsigned short* __restrict__ colu, int* __restrict__ cnt,
    float* __restrict__ dinv) {
    __shared__ int lcnt[PART_SIZE];
    const int p = blockIdx.x;                 // 0..NPARTS-1
    if (threadIdx.x < PART_SIZE) lcnt[threadIdx.x] = 0;
    __syncthreads();
    const int base = p << PART_SHIFT;
    const int n = min(qcnt[(size_t)p * QSTRIDE], QCAP2);
    const unsigned int* qp = queue + (size_t)p * QCAP2;
    for (int i = threadIdx.x; i < n; i += 256) {
        unsigned int pk = qp[i];
        int dl = (pk >> 16) & (PART_SIZE - 1);
        int s  = pk & 0xFFFFu;
        int pos = atomicAdd(&lcnt[dl], 1);
        if (pos < CAP)
            colu[(size_t)(base + dl) * CAP + pos] = (unsigned short)s;
    }
    __syncthreads();
    if (threadIdx.x < PART_SIZE) {
        int d = base + threadIdx.x;
        if (d < N_NODES) {
            int c = lcnt[threadIdx.x];
            cnt[d] = c;                               // true degree
            dinv[d] = rsqrtf((float)c + 1.0f);        // +1 self-loop
        }
    }
}

__global__ __launch_bounds__(256) void make_dinv(const int* __restrict__ cnt,
                                                 float* __restrict__ dinv) {
    int v = blockIdx.x * blockDim.x + threadIdx.x;
    if (v < N_NODES) dinv[v] = rsqrtf((float)cnt[v] + 1.0f);  // +1 self-loop
}

// ---------------- GEMM (MFMA): msg = dinv[row]*(h@W) ----------------
__global__ __launch_bounds__(256) void gemm_scale(
    const void* hsrc, int kind, int b_bf16,
    const unsigned short* __restrict__ Wt,
    const float* __restrict__ dinv,
    const float* __restrict__ mode,
    const float* __restrict__ alpha, const float* __restrict__ delta,
    unsigned short* A, float* __restrict__ B, int write_b) {
    const int wave = threadIdx.x >> 6;
    const int lane = threadIdx.x & 63;
    const int quad = lane >> 4;
    const int nidx = lane & 15;
    const int row0 = blockIdx.x * 16;

    short8 afrag[4];
    if (kind == 0) {
        if (mode[0] > 0.5f) {
            const float* xf = (const float*)hsrc;
            #pragma unroll
            for (int kk = 0; kk < 4; ++kk) {
                const float4v* xr = (const float4v*)(xf + (size_t)(row0 + nidx) * DIM + kk * 32 + quad * 8);
                float4v p0 = xr[0], p1 = xr[1];
                #pragma unroll
                for (int j = 0; j < 4; ++j) {
                    afrag[kk][j]     = (short)f32_to_bf16_bits(p0[j]);
                    afrag[kk][4 + j] = (short)f32_to_bf16_bits(p1[j]);
                }
            }
        } else {
            const unsigned short* hu = (const unsigned short*)hsrc;
            #pragma unroll
            for (int kk = 0; kk < 4; ++kk)
                afrag[kk] = *(const short8*)(hu + (size_t)(row0 + nidx) * DIM + kk * 32 + quad * 8);
        }
    } else if (b_bf16) {
        const unsigned short* Bh = (const unsigned short*)hsrc;
        const float dv = dinv[row0 + nidx];
        #pragma unroll
        for (int kk = 0; kk < 4; ++kk) {
            short8 braw = *(const short8*)(Bh + (size_t)(row0 + nidx) * DIM + kk * 32 + quad * 8);
            const float* ap = alpha + kk * 32 + quad * 8;
            const float* dp = delta + kk * 32 + quad * 8;
            float4v A0 = *(const float4v*)ap, A1 = *(const float4v*)(ap + 4);
            float4v D0 = *(const float4v*)dp, D1 = *(const float4v*)(dp + 4);
            #pragma unroll
            for (int j = 0; j < 4; ++j) {
                float v0 = bf16_bits_to_f32((unsigned short)braw[j]);
                float v1 = bf16_bits_to_f32((unsigned short)braw[4 + j]);
                float h0 = fmaxf(fmaf(A0[j] * dv, v0, D0[j]), 0.f);
                float h1 = fmaxf(fmaf(A1[j] * dv, v1, D1[j]), 0.f);
                afrag[kk][j]     = (short)f32_to_bf16_bits(h0);
                afrag[kk][4 + j] = (short)f32_to_bf16_bits(h1);
            }
        }
    } else {
        const float* Bf = (const float*)hsrc;
        const float dv = dinv[row0 + nidx];
        #pragma unroll
        for (int kk = 0; kk < 4; ++kk) {
            const float* bp = Bf + (size_t)(row0 + nidx) * DIM + kk * 32 + quad * 8;
            float4v p0 = *(const float4v*)bp;
            float4v p1 = *(const float4v*)(bp + 4);
            const float* ap = alpha + kk * 32 + quad * 8;
            const float* dp = delta + kk * 32 + quad * 8;
            float4v A0 = *(const float4v*)ap, A1 = *(const float4v*)(ap + 4);
            float4v D0 = *(const float4v*)dp, D1 = *(const float4v*)(dp + 4);
            #pragma unroll
            for (int j = 0; j < 4; ++j) {
                float h0 = fmaxf(fmaf(A0[j] * dv, p0[j], D0[j]), 0.f);
                float h1 = fmaxf(fmaf(A1[j] * dv, p1[j], D1[j]), 0.f);
                afrag[kk][j]     = (short)f32_to_bf16_bits(h0);
                afrag[kk][4 + j] = (short)f32_to_bf16_bits(h1);
            }
        }
    }

    short8 bfrag[2][4];
    #pragma unroll
    for (int half = 0; half < 2; ++half) {
        int c = wave * 32 + half * 16 + nidx;
        #pragma unroll
        for (int kk = 0; kk < 4; ++kk)
            bfrag[half][kk] = *(const short8*)(Wt + (size_t)c * DIM + kk * 32 + quad * 8);
    }

    float4v acc0 = {0.f, 0.f, 0.f, 0.f};
    float4v acc1 = {0.f, 0.f, 0.f, 0.f};
    #pragma unroll
    for (int kk = 0; kk < 4; ++kk) {
        acc0 = __builtin_amdgcn_mfma_f32_16x16x32_bf16(afrag[kk], bfrag[0][kk], acc0, 0, 0, 0);
        acc1 = __builtin_amdgcn_mfma_f32_16x16x32_bf16(afrag[kk], bfrag[1][kk], acc1, 0, 0, 0);
    }

    #pragma unroll
    for (int r = 0; r < 4; ++r) {
        int row = row0 + quad * 4 + r;
        float d = dinv[row];
        float v0 = acc0[r] * d;
        float v1 = acc1[r] * d;
        size_t i0 = (size_t)row * DIM + wave * 32 + nidx;
        size_t i1 = i0 + 16;
        A[i0] = f32_to_bf16_bits(v0);
        A[i1] = f32_to_bf16_bits(v1);
        if (write_b) { B[i0] = v0; B[i1] = v1; }
    }
}

// ---------------- gather v3 (+fused BN reduce & coefs via done-counter) ----------------
// 1 node/wave, 16 lanes/edge x 16B: one wave-inst covers 4 edges. Loop fully unrolled
// over CAP in 3 chunks of 16 edges -> 4 independent uint4 loads in flight (round-5
// lesson: dynamic loop kept only 2 loads in flight). deg is wave-uniform -> guard is
// divergence-free. After partial write, blocks 0..124 wait on doneG (fence+counter,
// same proven pattern as old reduce_coefs) and run the BN reduction inline; the last
// reducer computes alpha/delta and re-zeros stats/doneG/doneR (graph-replay safe).
#define FMA8(vv, ww) do { \
    a0 = fmaf(ww, bf16_lo(vv.x), a0); a1 = fmaf(ww, bf16_hi(vv.x), a1); \
    a2 = fmaf(ww, bf16_lo(vv.y), a2); a3 = fmaf(ww, bf16_hi(vv.y), a3); \
    a4 = fmaf(ww, bf16_lo(vv.z), a4); a5 = fmaf(ww, bf16_hi(vv.z), a5); \
    a6 = fmaf(ww, bf16_lo(vv.w), a6); a7 = fmaf(ww, bf16_hi(vv.w), a7); } while (0)

template <int SC>
__global__ __launch_bounds__(256) void gather_fused(
    const int* __restrict__ cnt, const unsigned short* __restrict__ colu,
    const unsigned short* __restrict__ A,
    const float* __restrict__ dinv, const float* __restrict__ pf32, int l,
    unsigned short* __restrict__ Bh, float* __restrict__ partial,
    float* __restrict__ stats, int* __restrict__ doneG, int* __restrict__ doneR,
    float* __restrict__ alpha, float* __restrict__ delta) {
    __shared__ float sacc[4][128], sacc2[4][128];
    const float* bias = pf32 + l * 128;
    const int wave = threadIdx.x >> 6;
    const int lane = threadIdx.x & 63;
    const int g    = lane >> 4;        // edge slot within a 4-edge chunk
    const int c8   = (lane & 15) * 8;  // 8 columns (16B) per lane
    const int node = blockIdx.x * 4 + wave;   // exact: 12500*4 = 50000
    const int deg  = min(cnt[node], CAP);
    const int lo   = node * CAP;
    const float dv = dinv[node];

    // preload edge list + weights into per-lane registers (one coalesced pass)
    int   cv = (lane < deg) ? (int)colu[lo + lane] : 0;
    float wv = (lane < deg) ? (SC ? dinv[cv] : 1.0f) : 0.0f;

    // init accumulators with self-loop term (counted once via group 0)
    float a0, a1, a2, a3, a4, a5, a6, a7;
    {
        uint4 sv = *(const uint4*)(A + (size_t)node * DIM + c8);
        const float scl = (g == 0) ? (SC ? dv : 1.0f) : 0.0f;
        a0 = scl * bf16_lo(sv.x); a1 = scl * bf16_hi(sv.x);
        a2 = scl * bf16_lo(sv.y); a3 = scl * bf16_hi(sv.y);
        a4 = scl * bf16_lo(sv.z); a5 = scl * bf16_hi(sv.z);
        a6 = scl * bf16_lo(sv.w); a7 = scl * bf16_hi(sv.w);
    }

    // 16 edges per chunk, fully unrolled (CAP=48 -> 3 chunks), zero-weight padding
    #pragma unroll
    for (int j = 0; j < CAP; j += 16) {
        if (j < deg) {   // wave-uniform condition: deg identical across the wave
            int i0 = j + g, i1 = j + 4 + g, i2 = j + 8 + g, i3 = j + 12 + g;
            int   s0 = __shfl(cv, i0);  float w0 = __shfl(wv, i0);
            int   s1 = __shfl(cv, i1);  float w1 = __shfl(wv, i1);
            int   s2 = __shfl(cv, i2);  float w2 = __shfl(wv, i2);
            int   s3 = __shfl(cv, i3);  float w3 = __shfl(wv, i3);
            uint4 v0 = *(const uint4*)(A + (size_t)s0 * DIM + c8);
            uint4 v1 = *(const uint4*)(A + (size_t)s1 * DIM + c8);
            uint4 v2 = *(const uint4*)(A + (size_t)s2 * DIM + c8);
            uint4 v3 = *(const uint4*)(A + (size_t)s3 * DIM + c8);
            FMA8(v0, w0);
            FMA8(v1, w1);
            FMA8(v2, w2);
            FMA8(v3, w3);
        }
    }

    // reduce across the 4 edge-groups (lane bits 4,5)
    a0 += __shfl_xor(a0, 16); a0 += __shfl_xor(a0, 32);
    a1 += __shfl_xor(a1, 16); a1 += __shfl_xor(a1, 32);
    a2 += __shfl_xor(a2, 16); a2 += __shfl_xor(a2, 32);
    a3 += __shfl_xor(a3, 16); a3 += __shfl_xor(a3, 32);
    a4 += __shfl_xor(a4, 16); a4 += __shfl_xor(a4, 32);
    a5 += __shfl_xor(a5, 16); a5 += __shfl_xor(a5, 32);
    a6 += __shfl_xor(a6, 16); a6 += __shfl_xor(a6, 32);
    a7 += __shfl_xor(a7, 16); a7 += __shfl_xor(a7, 32);

    if (lane < 16) {
        unsigned int p0 = (unsigned int)f32_to_bf16_bits(a0) | ((unsigned int)f32_to_bf16_bits(a1) << 16);
        unsigned int p1 = (unsigned int)f32_to_bf16_bits(a2) | ((unsigned int)f32_to_bf16_bits(a3) << 16);
        unsigned int p2 = (unsigned int)f32_to_bf16_bits(a4) | ((unsigned int)f32_to_bf16_bits(a5) << 16);
        unsigned int p3 = (unsigned int)f32_to_bf16_bits(a6) | ((unsigned int)f32_to_bf16_bits(a7) << 16);
        uint4 st = {p0, p1, p2, p3};
        *(uint4*)(Bh + (size_t)node * DIM + c8) = st;
        float4 b0 = *(const float4*)(bias + c8);
        float4 b1 = *(const float4*)(bias + c8 + 4);
        float v0 = fmaf(dv, a0, b0.x), v1 = fmaf(dv, a1, b0.y);
        float v2 = fmaf(dv, a2, b0.z), v3 = fmaf(dv, a3, b0.w);
        float v4 = fmaf(dv, a4, b1.x), v5 = fmaf(dv, a5, b1.y);
        float v6 = fmaf(dv, a6, b1.z), v7 = fmaf(dv, a7, b1.w);
        sacc[wave][c8]     = v0;  sacc2[wave][c8]     = v0 * v0;
        sacc[wave][c8 + 1] = v1;  sacc2[wave][c8 + 1] = v1 * v1;
        sacc[wave][c8 + 2] = v2;  sacc2[wave][c8 + 2] = v2 * v2;
        sacc[wave][c8 + 3] = v3;  sacc2[wave][c8 + 3] = v3 * v3;
        sacc[wave][c8 + 4] = v4;  sacc2[wave][c8 + 4] = v4 * v4;
        sacc[wave][c8 + 5] = v5;  sacc2[wave][c8 + 5] = v5 * v5;
        sacc[wave][c8 + 6] = v6;  sacc2[wave][c8 + 6] = v6 * v6;
        sacc[wave][c8 + 7] = v7;  sacc2[wave][c8 + 7] = v7 * v7;
    }
    __syncthreads();
    const int t = threadIdx.x;
    float s;
    if (t < 128) s = sacc[0][t] + sacc[1][t] + sacc[2][t] + sacc[3][t];
    else { int c = t - 128; s = sacc2[0][c] + sacc2[1][c] + sacc2[2][c] + sacc2[3][c]; }
    partial[(size_t)blockIdx.x * 256 + t] = s;   // coalesced, no atomics

    // ---- publish completion (all threads fence their own writes, then one bump) ----
    __threadfence();
    __syncthreads();
    if (t == 0) atomicAdd(doneG, 1);

    // ---- blocks 0..RED_BLOCKS-1: inline BN reduction + coefs (saves a dispatch) ----
    if (blockIdx.x < RED_BLOCKS) {
        if (t == 0) {
            while (atomicAdd(doneG, 0) < GATHER_BLOCKS)
                __builtin_amdgcn_s_sleep(16);
        }
        __syncthreads();
        __threadfence();   // acquire: invalidate stale cached partial lines
        const int rows = GATHER_BLOCKS / RED_BLOCKS;   // 100
        const int r0 = blockIdx.x * rows;
        float rs = 0.f;
        for (int i = 0; i < rows; ++i)
            rs += partial[(size_t)(r0 + i) * 256 + t];
        atomicAdd(&stats[t], rs);
        __threadfence();
        __shared__ int lastFlag;
        if (t == 0) lastFlag = (atomicAdd(doneR, 1) == RED_BLOCKS - 1) ? 1 : 0;
        __syncthreads();
        if (lastFlag && t < 128) {
            float cs  = atomicAdd(&stats[t], 0.0f);
            float css = atomicAdd(&stats[t + 128], 0.0f);
            const float invN = 1.0f / N_NODES;
            float mu = cs * invN;
            float var = css * invN - mu * mu;
            float istd = rsqrtf(var + BN_EPS);
            float gg = pf32[384 + l * 128 + t];
            float bt = pf32[768 + l * 128 + t];
            float bi = pf32[l * 128 + t];
            float al = gg * istd;
            alpha[t] = al;
            delta[t] = al * (bi - mu) + bt;
            atomicExch(&stats[t], 0.0f);
            atomicExch(&stats[t + 128], 0.0f);
            if (t == 0) { atomicExch(doneR, 0); atomicExch(doneG, 0); }
        }
    }
}

// ---------------- BN coefs (fallback path only) ----------------
__global__ __launch_bounds__(128) void bn_coefs(
    const float* __restrict__ pf32, int l,
    float* __restrict__ colsum, float* __restrict__ colsumsq,
    float* __restrict__ alpha, float* __restrict__ delta) {
    int c = threadIdx.x;
    const float invN = 1.0f / N_NODES;
    float mu = colsum[c] * invN;
    float var = colsumsq[c] * invN - mu * mu;
    float istd = rsqrtf(var + BN_EPS);
    float gg = pf32[384 + l * 128 + c];
    float bt = pf32[768 + l * 128 + c];
    float bi = pf32[l * 128 + c];
    float al = gg * istd;
    alpha[c] = al;
    delta[c] = al * (bi - mu) + bt;
    colsum[c] = 0.f;
    colsumsq[c] = 0.f;
}

// ---------------- fallback path (ws too small): hist + scatter + bn_reduce ----------------
__global__ __launch_bounds__(256) void hist_dst(const int* __restrict__ dst,
                                                int* __restrict__ cnt) {
    int e = blockIdx.x * blockDim.x + threadIdx.x;
    if (e < N_EDGES) atomicAdd(&cnt[dst[e]], 1);
}

__global__ __launch_bounds__(256) void scatter_edges(
    const int* __restrict__ src, const int* __restrict__ dst,
    const unsigned short* __restrict__ A, float* __restrict__ B) {
    int t = blockIdx.x * blockDim.x + threadIdx.x;
    int e = t >> 4;
    if (e >= N_EDGES) return;
    int f = (t & 15) * 8;
    int s = src[e], d = dst[e];
    short8 v = *(const short8*)(A + (size_t)s * DIM + f);
    float* bp = B + (size_t)d * DIM + f;
    #pragma unroll
    for (int j = 0; j < 8; ++j)
        atomicAdd(bp + j, bf16_bits_to_f32((unsigned short)v[j]));
}

__global__ __launch_bounds__(256) void bn_reduce(
    const float* __restrict__ B, const float* __restrict__ dinv,
    const float* __restrict__ bias,
    float* __restrict__ colsum, float* __restrict__ colsumsq) {
    int c = threadIdx.x & 127;
    int half = threadIdx.x >> 7;
    float bb = bias[c];
    float s = 0.f, s2 = 0.f;
    for (int row = blockIdx.x * 2 + half; row < N_NODES; row += gridDim.x * 2) {
        float v = dinv[row] * B[(size_t)row * DIM + c] + bb;
        s += v;
        s2 += v * v;
    }
    __shared__ float ls[128], ls2[128];
    if (half == 1) { ls[c] = s; ls2[c] = s2; }
    __syncthreads();
    if (half == 0) {
        atomicAdd(&colsum[c], s + ls[c]);
        atomicAdd(&colsumsq[c], s2 + ls2[c]);
    }
}

// ---------------- final output: BN apply via coefs + ReLU, dtype per mode ----------------
__global__ __launch_bounds__(256) void bn_apply(
    const void* __restrict__ Bv, int b_bf16,
    const float* __restrict__ dinv,
    const float* __restrict__ alpha, const float* __restrict__ delta,
    const float* __restrict__ mode, void* __restrict__ out) {
    int t = blockIdx.x * blockDim.x + threadIdx.x;
    if (t >= N_NODES * DIM) return;
    int row = t >> 7, c = t & 127;
    float bval = b_bf16 ? bf16_bits_to_f32(((const unsigned short*)Bv)[t])
                        : ((const float*)Bv)[t];
    float r = fmaxf(fmaf(alpha[c] * dinv[row], bval, delta[c]), 0.f);
    if (mode[0] > 0.5f)
        ((float*)out)[t] = r;
    else
        ((unsigned short*)out)[t] = f32_to_bf16_bits(r);
}

extern "C" void kernel_launch(void* const* d_in, const int* in_sizes, int n_in,
                              void* d_out, int out_size, void* d_ws, size_t ws_size,
                              hipStream_t stream) {
    const void* x  = d_in[0];
    const int*  ei = (const int*)d_in[1];
    const void* W  = d_in[2];
    const void* b  = d_in[3];
    const void* g  = d_in[4];
    const void* be = d_in[5];

    unsigned short* hA = (unsigned short*)d_out;  // bf16 message buffer

    char* ws = (char*)d_ws;
    size_t off = 0;
    auto alloc = [&](size_t bytes) {
        char* p = ws + off;
        off = (off + bytes + 255) & ~(size_t)255;
        return p;
    };
    float* dinv     = (float*)alloc((size_t)N_NODES * 4);
    float* B        = (float*)alloc((size_t)N_NODES * DIM * 4);  // f32 for fallback; CSR uses as bf16
    unsigned short* Wt = (unsigned short*)alloc((size_t)3 * DIM * DIM * 2);
    float* pf32     = (float*)alloc(3 * 3 * DIM * 4);
    float* stats    = (float*)alloc(256 * 4);   // colsum[0:128] || colsumsq[128:256]
    float* alphaB   = (float*)alloc(128 * 4);
    float* deltaB   = (float*)alloc(128 * 4);
    float* mode     = (float*)alloc(64 * 4);
    int*   done     = (int*)alloc(64 * 4);      // done[0]=gather, done[1]=reducers
    int*   cnt      = (int*)alloc((size_t)N_NODES * 4);
    unsigned short* colu = (unsigned short*)alloc((size_t)N_NODES * CAP * 2);  // 4.8MB
    float* partial  = (float*)alloc((size_t)GATHER_BLOCKS * 256 * 4);          // 12.8MB
    int*   qcnt     = (int*)alloc((size_t)NPARTS * QSTRIDE * 4);               // 50KB padded
    // queue aliases partial (used strictly before the first gather writes partial)
    unsigned int* queue = (unsigned int*)partial;   // NPARTS*QCAP2*4 = 4.0MB <= 12.8MB
    const bool csr_ok = (ws_size >= off) || (ws_size == 0);
    float* colsum = stats;
    float* colsumsq = stats + 128;
    unsigned short* Bh = (unsigned short*)B;

    const int* srcv = ei;            // edge_index[0]
    const int* dstv = ei + N_EDGES;  // edge_index[1]

    const int PREP_BLOCKS = (3 * DIM * DIM + 3 * 3 * DIM + 255) / 256;
    prep<<<PREP_BLOCKS, 256, 0, stream>>>(
        (const unsigned short*)x, W, b, g, be, mode, Wt, pf32, qcnt, stats, done);

    if (csr_ok) {
        // LDS counting-sort binning (196 blocks, dispatched first) || layer-0 GEMM
        fused_a<<<BIN_BLOCKS + GEMM_BLOCKS, 256, 0, stream>>>(
            srcv, dstv, qcnt, queue, x, Wt, mode, hA);
        // phase B: per-part queues -> padded CSR + cnt + dinv
        csr_build<<<NPARTS, 256, 0, stream>>>(qcnt, queue, colu, cnt, dinv);

        for (int l = 0; l < 3; ++l) {
            if (l > 0)
                gemm_scale<<<GEMM_BLOCKS, 256, 0, stream>>>(
                    (const void*)B, 2, 1, Wt + (size_t)l * DIM * DIM, dinv, mode,
                    alphaB, deltaB, hA, B, 0);
            if (l == 0)
                gather_fused<1><<<GATHER_BLOCKS, 256, 0, stream>>>(
                    cnt, colu, hA, dinv, pf32, l, Bh, partial, stats,
                    done, done + 1, alphaB, deltaB);
            else
                gather_fused<0><<<GATHER_BLOCKS, 256, 0, stream>>>(
                    cnt, colu, hA, dinv, pf32, l, Bh, partial, stats,
                    done, done + 1, alphaB, deltaB);
            if (l == 2)
                bn_apply<<<(N_NODES * DIM) / 256, 256, 0, stream>>>(
                    (const void*)B, 1, dinv, alphaB, deltaB, mode, d_out);
        }
    } else {
        // fallback: original scatter pipeline (all layers use dinv-scaled gemm)
        zero_int<<<(N_NODES + 255) / 256, 256, 0, stream>>>(cnt, N_NODES);
        hist_dst<<<(N_EDGES + 255) / 256, 256, 0, stream>>>(dstv, cnt);
        make_dinv<<<(N_NODES + 255) / 256, 256, 0, stream>>>(cnt, dinv);

        for (int l = 0; l < 3; ++l) {
            const void* hin = (l == 0) ? x : (const void*)B;
            gemm_scale<<<GEMM_BLOCKS, 256, 0, stream>>>(
                hin, (l == 0) ? 0 : 2, 0, Wt + (size_t)l * DIM * DIM, dinv, mode,
                alphaB, deltaB, hA, B, 1);
            scatter_edges<<<(N_EDGES * 16) / 256, 256, 0, stream>>>(srcv, dstv, hA, B);
            bn_reduce<<<256, 256, 0, stream>>>(B, dinv, pf32 + l * 128, colsum, colsumsq);
            bn_coefs<<<1, 128, 0, stream>>>(pf32, l, colsum, colsumsq, alphaB, deltaB);
            if (l == 2)
                bn_apply<<<(N_NODES * DIM) / 256, 256, 0, stream>>>(
                    (const void*)B, 0, dinv, alphaB, deltaB, mode, d_out);
        }
    }
}

// Round 7
// 333.845 us; speedup vs baseline: 11.9900x; 11.9900x over previous
//
#include <hip/hip_runtime.h>
#include <hip/hip_bf16.h>

#define N_NODES 50000
#define N_EDGES 800000
#define DIM 128
#define BN_EPS 1e-5f
#define GATHER_BLOCKS (N_NODES / 4)           // 12500, 1 node per wave
#define RED_BLOCKS 125
#define CAP 48                                // padded CSR row capacity (actual max deg ~37)

// ---- CSR build constants (LDS counting-sort binning) ----
#define PART_SHIFT 7
#define PART_SIZE 128
#define NPARTS ((N_NODES + PART_SIZE - 1) / PART_SIZE)   // 391
#define QSTRIDE 32                                       // qcnt pad: 1 counter / 128B line
#define BIN_EPB 4096                                     // edges per binning block
#define BIN_BLOCKS ((N_EDGES + BIN_EPB - 1) / BIN_EPB)   // 196
#define QCAP2 2560                                       // per-part queue cap (mean 2046, +11 sigma)
#define GEMM_BLOCKS (N_NODES / 16)                       // 3125

typedef __attribute__((ext_vector_type(8))) short short8;
typedef __attribute__((ext_vector_type(4))) float float4v;

__device__ __forceinline__ float bf16_bits_to_f32(unsigned short u) {
    union { unsigned int i; float f; } c;
    c.i = ((unsigned int)u) << 16;
    return c.f;
}

__device__ __forceinline__ float bf16_lo(unsigned int u) {
    union { unsigned int i; float f; } c;
    c.i = u << 16;
    return c.f;
}

__device__ __forceinline__ float bf16_hi(unsigned int u) {
    union { unsigned int i; float f; } c;
    c.i = u & 0xFFFF0000u;
    return c.f;
}

__device__ __forceinline__ unsigned short f32_to_bf16_bits(float f) {
    union { float f; unsigned int i; } c;
    c.f = f;
    unsigned int lsb = (c.i >> 16) & 1u;
    c.i += 0x7FFFu + lsb;   // RNE
    return (unsigned short)(c.i >> 16);
}

// ---------------- zero-init helpers (fallback path) ----------------
__global__ __launch_bounds__(256) void zero_int(int* __restrict__ p, int n) {
    int i = blockIdx.x * blockDim.x + threadIdx.x;
    if (i < n) p[i] = 0;
}

// ---------------- prep: dtype sniff (per-block, local) + param convert + zeroing ----------------
// Merges sniff + convert_params + zero_aux into ONE dispatch. Each block recomputes the
// 512-elem dtype sniff locally (1KB, L2-hot) to break the cross-dispatch dependency.
__global__ __launch_bounds__(256) void prep(
    const unsigned short* __restrict__ xu,
    const void* __restrict__ W, const void* __restrict__ b,
    const void* __restrict__ g, const void* __restrict__ be,
    float* __restrict__ modeg, unsigned short* __restrict__ Wt,
    float* __restrict__ pf32,
    int* __restrict__ qcnt, float* __restrict__ stats, int* __restrict__ done) {
    __shared__ int okc;
    if (threadIdx.x == 0) okc = 0;
    __syncthreads();
    int ok = 0;
    for (int i = threadIdx.x; i < 512; i += 256) {
        unsigned e = (xu[i] >> 7) & 0xFFu;
        if (e >= 96u && e <= 159u) ok++;
    }
    atomicAdd(&okc, ok);
    __syncthreads();
    const bool mf32 = okc < 480;   // same rule as old sniff: >=480 -> bf16(0), else f32(1)

    if (blockIdx.x == 0) {
        if (threadIdx.x == 0) { modeg[0] = mf32 ? 1.0f : 0.0f; done[0] = 0; done[1] = 0; }
        for (int i = threadIdx.x; i < NPARTS; i += 256) qcnt[(size_t)i * QSTRIDE] = 0;
        stats[threadIdx.x] = 0.0f;
    }

    int i = blockIdx.x * 256 + threadIdx.x;
    const int NW = 3 * DIM * DIM;  // 49152
    if (i < NW) {
        int l = i >> 14;
        int rem = i & 16383;
        int k = rem >> 7;
        int n = rem & 127;
        unsigned short v = mf32 ? f32_to_bf16_bits(((const float*)W)[i])
                                : ((const unsigned short*)W)[i];
        Wt[(size_t)l * DIM * DIM + (size_t)n * DIM + k] = v;  // transposed
    } else if (i < NW + 3 * 3 * DIM) {
        int p = i - NW;
        int which = p / 384;         // 0=b 1=gamma 2=beta
        int r = p - which * 384;
        const void* srcp = (which == 0) ? b : (which == 1) ? g : be;
        float v = mf32 ? ((const float*)srcp)[r]
                       : bf16_bits_to_f32(((const unsigned short*)srcp)[r]);
        pf32[which * 384 + r] = v;
    }
}

// ---------------- fused: LDS counting-sort binning (196 blocks) || layer-0 GEMM ----------------
__global__ __launch_bounds__(256) void fused_a(
    const int* __restrict__ src, const int* __restrict__ dst,
    int* __restrict__ qcnt, unsigned int* __restrict__ queue,
    const void* __restrict__ x, const unsigned short* __restrict__ Wt,
    const float* __restrict__ mode, unsigned short* __restrict__ A) {
    __shared__ int lcnt[NPARTS];
    __shared__ int loff[NPARTS];   // scan result, then working offsets for pass 2
    __shared__ int adj[NPARTS];    // gbase - pref
    __shared__ unsigned short staged16[BIN_EPB];  // part-sorted local edge ids (8KB)
    __shared__ int sortedN;
    const int bid = blockIdx.x;
    if (bid < BIN_BLOCKS) {
        const int t = threadIdx.x;
        const int blk0 = bid * BIN_EPB;
        const int nval = min(BIN_EPB, N_EDGES - blk0);
        for (int i = t; i < NPARTS; i += 256) lcnt[i] = 0;
        __syncthreads();
        // pass 1: count parts
        for (int li = t; li < nval; li += 256) {
            int d = dst[blk0 + li];
            if ((unsigned)d < (unsigned)N_NODES)
                atomicAdd(&lcnt[d >> PART_SHIFT], 1);
        }
        __syncthreads();
        // wave-0 exclusive prefix scan over NPARTS -> loff (shuffle-based)
        if (t < 64) {
            int base = 0;
            for (int c = 0; c < (NPARTS + 63) / 64; ++c) {
                int idx = c * 64 + t;
                int orig = (idx < NPARTS) ? lcnt[idx] : 0;
                int v = orig;
                #pragma unroll
                for (int o = 1; o < 64; o <<= 1) {
                    int up = __shfl_up(v, o);
                    if (t >= o) v += up;
                }
                if (idx < NPARTS) loff[idx] = base + v - orig;
                base += __shfl(v, 63);
            }
            if (t == 0) sortedN = base;
        }
        __syncthreads();
        // one global reservation per (block, part); adj = gbase - pref
        for (int i = t; i < NPARTS; i += 256) {
            int c = lcnt[i];
            int gb = c ? atomicAdd(&qcnt[(size_t)i * QSTRIDE], c) : 0;
            adj[i] = gb - loff[i];
        }
        __syncthreads();
        // pass 2: LDS sort local edge ids by part (dst re-read, L1-hot window)
        for (int li = t; li < nval; li += 256) {
            int d = dst[blk0 + li];
            if ((unsigned)d < (unsigned)N_NODES) {
                int part = d >> PART_SHIFT;
                int pos = atomicAdd(&loff[part], 1);
                staged16[pos] = (unsigned short)li;
            }
        }
        __syncthreads();
        // output: dense per-part runs; re-derive src/dst (both windows L1-resident)
        const int nOut = sortedN;
        for (int i = t; i < nOut; i += 256) {
            int li = staged16[i];
            int d = dst[blk0 + li];
            int s = src[blk0 + li];
            int part = d >> PART_SHIFT;
            int gp = adj[part] + i;
            if (gp >= 0 && gp < QCAP2)
                queue[(size_t)part * QCAP2 + gp] =
                    (unsigned int)(s & 0xFFFF) |
                    ((unsigned int)(d & (PART_SIZE - 1)) << 16);
        }
        return;
    }
    // ---- layer-0 GEMM (kind 0, unscaled output) ----
    const int wave = threadIdx.x >> 6;
    const int lane = threadIdx.x & 63;
    const int quad = lane >> 4;
    const int nidx = lane & 15;
    const int row0 = (bid - BIN_BLOCKS) * 16;

    short8 afrag[4];
    if (mode[0] > 0.5f) {
        const float* xf = (const float*)x;
        #pragma unroll
        for (int kk = 0; kk < 4; ++kk) {
            const float4v* xr = (const float4v*)(xf + (size_t)(row0 + nidx) * DIM + kk * 32 + quad * 8);
            float4v p0 = xr[0], p1 = xr[1];
            #pragma unroll
            for (int j = 0; j < 4; ++j) {
                afrag[kk][j]     = (short)f32_to_bf16_bits(p0[j]);
                afrag[kk][4 + j] = (short)f32_to_bf16_bits(p1[j]);
            }
        }
    } else {
        const unsigned short* hu = (const unsigned short*)x;
        #pragma unroll
        for (int kk = 0; kk < 4; ++kk)
            afrag[kk] = *(const short8*)(hu + (size_t)(row0 + nidx) * DIM + kk * 32 + quad * 8);
    }

    short8 bfrag[2][4];
    #pragma unroll
    for (int half = 0; half < 2; ++half) {
        int c = wave * 32 + half * 16 + nidx;
        #pragma unroll
        for (int kk = 0; kk < 4; ++kk)
            bfrag[half][kk] = *(const short8*)(Wt + (size_t)c * DIM + kk * 32 + quad * 8);
    }

    float4v acc0 = {0.f, 0.f, 0.f, 0.f};
    float4v acc1 = {0.f, 0.f, 0.f, 0.f};
    #pragma unroll
    for (int kk = 0; kk < 4; ++kk) {
        acc0 = __builtin_amdgcn_mfma_f32_16x16x32_bf16(afrag[kk], bfrag[0][kk], acc0, 0, 0, 0);
        acc1 = __builtin_amdgcn_mfma_f32_16x16x32_bf16(afrag[kk], bfrag[1][kk], acc1, 0, 0, 0);
    }

    #pragma unroll
    for (int r = 0; r < 4; ++r) {
        int row = row0 + quad * 4 + r;
        size_t i0 = (size_t)row * DIM + wave * 32 + nidx;
        A[i0]      = f32_to_bf16_bits(acc0[r]);
        A[i0 + 16] = f32_to_bf16_bits(acc1[r]);
    }
}

// ---------------- phase B: drain per-part queue -> padded CSR, LDS-atomic positions ----------------
__global__ __launch_bounds__(256) void csr_build(
    const int* __restrict__ qcnt, const unsigned int* __restrict__ queue,
    unsigned short* __restrict__ colu, int* __restrict__ cnt,
    float* __restrict__ dinv) {
    __shared__ int lcnt[PART_SIZE];
    const int p = blockIdx.x;                 // 0..NPARTS-1
    if (threadIdx.x < PART_SIZE) lcnt[threadIdx.x] = 0;
    __syncthreads();
    const int base = p << PART_SHIFT;
    const int n = min(qcnt[(size_t)p * QSTRIDE], QCAP2);
    const unsigned int* qp = queue + (size_t)p * QCAP2;
    for (int i = threadIdx.x; i < n; i += 256) {
        unsigned int pk = qp[i];
        int dl = (pk >> 16) & (PART_SIZE - 1);
        int s  = pk & 0xFFFFu;
        int pos = atomicAdd(&lcnt[dl], 1);
        if (pos < CAP)
            colu[(size_t)(base + dl) * CAP + pos] = (unsigned short)s;
    }
    __syncthreads();
    if (threadIdx.x < PART_SIZE) {
        int d = base + threadIdx.x;
        if (d < N_NODES) {
            int c = lcnt[threadIdx.x];
            cnt[d] = c;                               // true degree
            dinv[d] = rsqrtf((float)c + 1.0f);        // +1 self-loop
        }
    }
}

__global__ __launch_bounds__(256) void make_dinv(const int* __restrict__ cnt,
                                                 float* __restrict__ dinv) {
    int v = blockIdx.x * blockDim.x + threadIdx.x;
    if (v < N_NODES) dinv[v] = rsqrtf((float)cnt[v] + 1.0f);  // +1 self-loop
}

// ---------------- GEMM (MFMA): msg = dinv[row]*(h@W) ----------------
__global__ __launch_bounds__(256) void gemm_scale(
    const void* hsrc, int kind, int b_bf16,
    const unsigned short* __restrict__ Wt,
    const float* __restrict__ dinv,
    const float* __restrict__ mode,
    const float* __restrict__ alpha, const float* __restrict__ delta,
    unsigned short* A, float* __restrict__ B, int write_b) {
    const int wave = threadIdx.x >> 6;
    const int lane = threadIdx.x & 63;
    const int quad = lane >> 4;
    const int nidx = lane & 15;
    const int row0 = blockIdx.x * 16;

    short8 afrag[4];
    if (kind == 0) {
        if (mode[0] > 0.5f) {
            const float* xf = (const float*)hsrc;
            #pragma unroll
            for (int kk = 0; kk < 4; ++kk) {
                const float4v* xr = (const float4v*)(xf + (size_t)(row0 + nidx) * DIM + kk * 32 + quad * 8);
                float4v p0 = xr[0], p1 = xr[1];
                #pragma unroll
                for (int j = 0; j < 4; ++j) {
                    afrag[kk][j]     = (short)f32_to_bf16_bits(p0[j]);
                    afrag[kk][4 + j] = (short)f32_to_bf16_bits(p1[j]);
                }
            }
        } else {
            const unsigned short* hu = (const unsigned short*)hsrc;
            #pragma unroll
            for (int kk = 0; kk < 4; ++kk)
                afrag[kk] = *(const short8*)(hu + (size_t)(row0 + nidx) * DIM + kk * 32 + quad * 8);
        }
    } else if (b_bf16) {
        const unsigned short* Bh = (const unsigned short*)hsrc;
        const float dv = dinv[row0 + nidx];
        #pragma unroll
        for (int kk = 0; kk < 4; ++kk) {
            short8 braw = *(const short8*)(Bh + (size_t)(row0 + nidx) * DIM + kk * 32 + quad * 8);
            const float* ap = alpha + kk * 32 + quad * 8;
            const float* dp = delta + kk * 32 + quad * 8;
            float4v A0 = *(const float4v*)ap, A1 = *(const float4v*)(ap + 4);
            float4v D0 = *(const float4v*)dp, D1 = *(const float4v*)(dp + 4);
            #pragma unroll
            for (int j = 0; j < 4; ++j) {
                float v0 = bf16_bits_to_f32((unsigned short)braw[j]);
                float v1 = bf16_bits_to_f32((unsigned short)braw[4 + j]);
                float h0 = fmaxf(fmaf(A0[j] * dv, v0, D0[j]), 0.f);
                float h1 = fmaxf(fmaf(A1[j] * dv, v1, D1[j]), 0.f);
                afrag[kk][j]     = (short)f32_to_bf16_bits(h0);
                afrag[kk][4 + j] = (short)f32_to_bf16_bits(h1);
            }
        }
    } else {
        const float* Bf = (const float*)hsrc;
        const float dv = dinv[row0 + nidx];
        #pragma unroll
        for (int kk = 0; kk < 4; ++kk) {
            const float* bp = Bf + (size_t)(row0 + nidx) * DIM + kk * 32 + quad * 8;
            float4v p0 = *(const float4v*)bp;
            float4v p1 = *(const float4v*)(bp + 4);
            const float* ap = alpha + kk * 32 + quad * 8;
            const float* dp = delta + kk * 32 + quad * 8;
            float4v A0 = *(const float4v*)ap, A1 = *(const float4v*)(ap + 4);
            float4v D0 = *(const float4v*)dp, D1 = *(const float4v*)(dp + 4);
            #pragma unroll
            for (int j = 0; j < 4; ++j) {
                float h0 = fmaxf(fmaf(A0[j] * dv, p0[j], D0[j]), 0.f);
                float h1 = fmaxf(fmaf(A1[j] * dv, p1[j], D1[j]), 0.f);
                afrag[kk][j]     = (short)f32_to_bf16_bits(h0);
                afrag[kk][4 + j] = (short)f32_to_bf16_bits(h1);
            }
        }
    }

    short8 bfrag[2][4];
    #pragma unroll
    for (int half = 0; half < 2; ++half) {
        int c = wave * 32 + half * 16 + nidx;
        #pragma unroll
        for (int kk = 0; kk < 4; ++kk)
            bfrag[half][kk] = *(const short8*)(Wt + (size_t)c * DIM + kk * 32 + quad * 8);
    }

    float4v acc0 = {0.f, 0.f, 0.f, 0.f};
    float4v acc1 = {0.f, 0.f, 0.f, 0.f};
    #pragma unroll
    for (int kk = 0; kk < 4; ++kk) {
        acc0 = __builtin_amdgcn_mfma_f32_16x16x32_bf16(afrag[kk], bfrag[0][kk], acc0, 0, 0, 0);
        acc1 = __builtin_amdgcn_mfma_f32_16x16x32_bf16(afrag[kk], bfrag[1][kk], acc1, 0, 0, 0);
    }

    #pragma unroll
    for (int r = 0; r < 4; ++r) {
        int row = row0 + quad * 4 + r;
        float d = dinv[row];
        float v0 = acc0[r] * d;
        float v1 = acc1[r] * d;
        size_t i0 = (size_t)row * DIM + wave * 32 + nidx;
        size_t i1 = i0 + 16;
        A[i0] = f32_to_bf16_bits(v0);
        A[i1] = f32_to_bf16_bits(v1);
        if (write_b) { B[i0] = v0; B[i1] = v1; }
    }
}

// ---------------- padded-CSR gather v3 + fused BN stats (NO device fences here!) ----------------
// Round-6 lesson: a device-scope __threadfence in all 12500 gather blocks = L2
// writeback/invalidate per block on non-coherent XCD L2s -> 3.4x fetch amplification,
// 30x slowdown. Gather now ends at the partial write; reduction is a separate narrow
// dispatch. Body: 1 node/wave, 16 lanes/edge x 16B, fully unrolled 3x16-edge chunks ->
// 4 independent uint4 loads in flight; deg is wave-uniform so the guard is divergence-free.
#define FMA8(vv, ww) do { \
    a0 = fmaf(ww, bf16_lo(vv.x), a0); a1 = fmaf(ww, bf16_hi(vv.x), a1); \
    a2 = fmaf(ww, bf16_lo(vv.y), a2); a3 = fmaf(ww, bf16_hi(vv.y), a3); \
    a4 = fmaf(ww, bf16_lo(vv.z), a4); a5 = fmaf(ww, bf16_hi(vv.z), a5); \
    a6 = fmaf(ww, bf16_lo(vv.w), a6); a7 = fmaf(ww, bf16_hi(vv.w), a7); } while (0)

template <int SC>
__global__ __launch_bounds__(256) void gather_csr(
    const int* __restrict__ cnt, const unsigned short* __restrict__ colu,
    const unsigned short* __restrict__ A,
    const float* __restrict__ dinv, const float* __restrict__ bias,
    unsigned short* __restrict__ Bh, float* __restrict__ partial) {
    __shared__ float sacc[4][128], sacc2[4][128];
    const int wave = threadIdx.x >> 6;
    const int lane = threadIdx.x & 63;
    const int g    = lane >> 4;        // edge slot within a 4-edge chunk
    const int c8   = (lane & 15) * 8;  // 8 columns (16B) per lane
    const int node = blockIdx.x * 4 + wave;   // exact: 12500*4 = 50000
    const int deg  = min(cnt[node], CAP);
    const int lo   = node * CAP;
    const float dv = dinv[node];

    // preload edge list + weights into per-lane registers (one coalesced pass)
    int   cv = (lane < deg) ? (int)colu[lo + lane] : 0;
    float wv = (lane < deg) ? (SC ? dinv[cv] : 1.0f) : 0.0f;

    // init accumulators with self-loop term (counted once via group 0)
    float a0, a1, a2, a3, a4, a5, a6, a7;
    {
        uint4 sv = *(const uint4*)(A + (size_t)node * DIM + c8);
        const float scl = (g == 0) ? (SC ? dv : 1.0f) : 0.0f;
        a0 = scl * bf16_lo(sv.x); a1 = scl * bf16_hi(sv.x);
        a2 = scl * bf16_lo(sv.y); a3 = scl * bf16_hi(sv.y);
        a4 = scl * bf16_lo(sv.z); a5 = scl * bf16_hi(sv.z);
        a6 = scl * bf16_lo(sv.w); a7 = scl * bf16_hi(sv.w);
    }

    // 16 edges per chunk, fully unrolled (CAP=48 -> 3 chunks), zero-weight padding
    #pragma unroll
    for (int j = 0; j < CAP; j += 16) {
        if (j < deg) {   // wave-uniform condition: deg identical across the wave
            int i0 = j + g, i1 = j + 4 + g, i2 = j + 8 + g, i3 = j + 12 + g;
            int   s0 = __shfl(cv, i0);  float w0 = __shfl(wv, i0);
            int   s1 = __shfl(cv, i1);  float w1 = __shfl(wv, i1);
            int   s2 = __shfl(cv, i2);  float w2 = __shfl(wv, i2);
            int   s3 = __shfl(cv, i3);  float w3 = __shfl(wv, i3);
            uint4 v0 = *(const uint4*)(A + (size_t)s0 * DIM + c8);
            uint4 v1 = *(const uint4*)(A + (size_t)s1 * DIM + c8);
            uint4 v2 = *(const uint4*)(A + (size_t)s2 * DIM + c8);
            uint4 v3 = *(const uint4*)(A + (size_t)s3 * DIM + c8);
            FMA8(v0, w0);
            FMA8(v1, w1);
            FMA8(v2, w2);
            FMA8(v3, w3);
        }
    }

    // reduce across the 4 edge-groups (lane bits 4,5)
    a0 += __shfl_xor(a0, 16); a0 += __shfl_xor(a0, 32);
    a1 += __shfl_xor(a1, 16); a1 += __shfl_xor(a1, 32);
    a2 += __shfl_xor(a2, 16); a2 += __shfl_xor(a2, 32);
    a3 += __shfl_xor(a3, 16); a3 += __shfl_xor(a3, 32);
    a4 += __shfl_xor(a4, 16); a4 += __shfl_xor(a4, 32);
    a5 += __shfl_xor(a5, 16); a5 += __shfl_xor(a5, 32);
    a6 += __shfl_xor(a6, 16); a6 += __shfl_xor(a6, 32);
    a7 += __shfl_xor(a7, 16); a7 += __shfl_xor(a7, 32);

    if (lane < 16) {
        unsigned int p0 = (unsigned int)f32_to_bf16_bits(a0) | ((unsigned int)f32_to_bf16_bits(a1) << 16);
        unsigned int p1 = (unsigned int)f32_to_bf16_bits(a2) | ((unsigned int)f32_to_bf16_bits(a3) << 16);
        unsigned int p2 = (unsigned int)f32_to_bf16_bits(a4) | ((unsigned int)f32_to_bf16_bits(a5) << 16);
        unsigned int p3 = (unsigned int)f32_to_bf16_bits(a6) | ((unsigned int)f32_to_bf16_bits(a7) << 16);
        uint4 st = {p0, p1, p2, p3};
        *(uint4*)(Bh + (size_t)node * DIM + c8) = st;
        float4 b0 = *(const float4*)(bias + c8);
        float4 b1 = *(const float4*)(bias + c8 + 4);
        float v0 = fmaf(dv, a0, b0.x), v1 = fmaf(dv, a1, b0.y);
        float v2 = fmaf(dv, a2, b0.z), v3 = fmaf(dv, a3, b0.w);
        float v4 = fmaf(dv, a4, b1.x), v5 = fmaf(dv, a5, b1.y);
        float v6 = fmaf(dv, a6, b1.z), v7 = fmaf(dv, a7, b1.w);
        sacc[wave][c8]     = v0;  sacc2[wave][c8]     = v0 * v0;
        sacc[wave][c8 + 1] = v1;  sacc2[wave][c8 + 1] = v1 * v1;
        sacc[wave][c8 + 2] = v2;  sacc2[wave][c8 + 2] = v2 * v2;
        sacc[wave][c8 + 3] = v3;  sacc2[wave][c8 + 3] = v3 * v3;
        sacc[wave][c8 + 4] = v4;  sacc2[wave][c8 + 4] = v4 * v4;
        sacc[wave][c8 + 5] = v5;  sacc2[wave][c8 + 5] = v5 * v5;
        sacc[wave][c8 + 6] = v6;  sacc2[wave][c8 + 6] = v6 * v6;
        sacc[wave][c8 + 7] = v7;  sacc2[wave][c8 + 7] = v7 * v7;
    }
    __syncthreads();
    const int t = threadIdx.x;
    float s;
    if (t < 128) s = sacc[0][t] + sacc[1][t] + sacc[2][t] + sacc[3][t];
    else { int c = t - 128; s = sacc2[0][c] + sacc2[1][c] + sacc2[2][c] + sacc2[3][c]; }
    partial[(size_t)blockIdx.x * 256 + t] = s;   // coalesced, no atomics
}

// ---------------- reduce partials -> stats, last block computes BN coefs ----------------
// Device fences are confined to this NARROW kernel (125 blocks) — cheap.
__global__ __launch_bounds__(256) void reduce_coefs(
    const float* __restrict__ partial, float* __restrict__ stats,
    int* __restrict__ done, const float* __restrict__ pf32, int l,
    float* __restrict__ alpha, float* __restrict__ delta) {
    const int t = threadIdx.x;
    const int rows = GATHER_BLOCKS / RED_BLOCKS;   // 100
    const int r0 = blockIdx.x * rows;
    float s = 0.f;
    for (int i = 0; i < rows; ++i)
        s += partial[(size_t)(r0 + i) * 256 + t];
    atomicAdd(&stats[t], s);
    __threadfence();
    __shared__ int lastFlag;
    if (t == 0) lastFlag = (atomicAdd(done, 1) == RED_BLOCKS - 1) ? 1 : 0;
    __syncthreads();
    if (lastFlag && t < 128) {
        float cs  = atomicAdd(&stats[t], 0.0f);
        float css = atomicAdd(&stats[t + 128], 0.0f);
        const float invN = 1.0f / N_NODES;
        float mu = cs * invN;
        float var = css * invN - mu * mu;
        float istd = rsqrtf(var + BN_EPS);
        float gg = pf32[384 + l * 128 + t];
        float bt = pf32[768 + l * 128 + t];
        float bi = pf32[l * 128 + t];
        float al = gg * istd;
        alpha[t] = al;
        delta[t] = al * (bi - mu) + bt;
        atomicExch(&stats[t], 0.0f);
        atomicExch(&stats[t + 128], 0.0f);
        if (t == 0) atomicExch(done, 0);
    }
}

// ---------------- BN coefs (fallback path only) ----------------
__global__ __launch_bounds__(128) void bn_coefs(
    const float* __restrict__ pf32, int l,
    float* __restrict__ colsum, float* __restrict__ colsumsq,
    float* __restrict__ alpha, float* __restrict__ delta) {
    int c = threadIdx.x;
    const float invN = 1.0f / N_NODES;
    float mu = colsum[c] * invN;
    float var = colsumsq[c] * invN - mu * mu;
    float istd = rsqrtf(var + BN_EPS);
    float gg = pf32[384 + l * 128 + c];
    float bt = pf32[768 + l * 128 + c];
    float bi = pf32[l * 128 + c];
    float al = gg * istd;
    alpha[c] = al;
    delta[c] = al * (bi - mu) + bt;
    colsum[c] = 0.f;
    colsumsq[c] = 0.f;
}

// ---------------- fallback path (ws too small): hist + scatter + bn_reduce ----------------
__global__ __launch_bounds__(256) void hist_dst(const int* __restrict__ dst,
                                                int* __restrict__ cnt) {
    int e = blockIdx.x * blockDim.x + threadIdx.x;
    if (e < N_EDGES) atomicAdd(&cnt[dst[e]], 1);
}

__global__ __launch_bounds__(256) void scatter_edges(
    const int* __restrict__ src, const int* __restrict__ dst,
    const unsigned short* __restrict__ A, float* __restrict__ B) {
    int t = blockIdx.x * blockDim.x + threadIdx.x;
    int e = t >> 4;
    if (e >= N_EDGES) return;
    int f = (t & 15) * 8;
    int s = src[e], d = dst[e];
    short8 v = *(const short8*)(A + (size_t)s * DIM + f);
    float* bp = B + (size_t)d * DIM + f;
    #pragma unroll
    for (int j = 0; j < 8; ++j)
        atomicAdd(bp + j, bf16_bits_to_f32((unsigned short)v[j]));
}

__global__ __launch_bounds__(256) void bn_reduce(
    const float* __restrict__ B, const float* __restrict__ dinv,
    const float* __restrict__ bias,
    float* __restrict__ colsum, float* __restrict__ colsumsq) {
    int c = threadIdx.x & 127;
    int half = threadIdx.x >> 7;
    float bb = bias[c];
    float s = 0.f, s2 = 0.f;
    for (int row = blockIdx.x * 2 + half; row < N_NODES; row += gridDim.x * 2) {
        float v = dinv[row] * B[(size_t)row * DIM + c] + bb;
        s += v;
        s2 += v * v;
    }
    __shared__ float ls[128], ls2[128];
    if (half == 1) { ls[c] = s; ls2[c] = s2; }
    __syncthreads();
    if (half == 0) {
        atomicAdd(&colsum[c], s + ls[c]);
        atomicAdd(&colsumsq[c], s2 + ls2[c]);
    }
}

// ---------------- final output: BN apply via coefs + ReLU, dtype per mode ----------------
__global__ __launch_bounds__(256) void bn_apply(
    const void* __restrict__ Bv, int b_bf16,
    const float* __restrict__ dinv,
    const float* __restrict__ alpha, const float* __restrict__ delta,
    const float* __restrict__ mode, void* __restrict__ out) {
    int t = blockIdx.x * blockDim.x + threadIdx.x;
    if (t >= N_NODES * DIM) return;
    int row = t >> 7, c = t & 127;
    float bval = b_bf16 ? bf16_bits_to_f32(((const unsigned short*)Bv)[t])
                        : ((const float*)Bv)[t];
    float r = fmaxf(fmaf(alpha[c] * dinv[row], bval, delta[c]), 0.f);
    if (mode[0] > 0.5f)
        ((float*)out)[t] = r;
    else
        ((unsigned short*)out)[t] = f32_to_bf16_bits(r);
}

extern "C" void kernel_launch(void* const* d_in, const int* in_sizes, int n_in,
                              void* d_out, int out_size, void* d_ws, size_t ws_size,
                              hipStream_t stream) {
    const void* x  = d_in[0];
    const int*  ei = (const int*)d_in[1];
    const void* W  = d_in[2];
    const void* b  = d_in[3];
    const void* g  = d_in[4];
    const void* be = d_in[5];

    unsigned short* hA = (unsigned short*)d_out;  // bf16 message buffer

    char* ws = (char*)d_ws;
    size_t off = 0;
    auto alloc = [&](size_t bytes) {
        char* p = ws + off;
        off = (off + bytes + 255) & ~(size_t)255;
        return p;
    };
    float* dinv     = (float*)alloc((size_t)N_NODES * 4);
    float* B        = (float*)alloc((size_t)N_NODES * DIM * 4);  // f32 for fallback; CSR uses as bf16
    unsigned short* Wt = (unsigned short*)alloc((size_t)3 * DIM * DIM * 2);
    float* pf32     = (float*)alloc(3 * 3 * DIM * 4);
    float* stats    = (float*)alloc(256 * 4);   // colsum[0:128] || colsumsq[128:256]
    float* alphaB   = (float*)alloc(128 * 4);
    float* deltaB   = (float*)alloc(128 * 4);
    float* mode     = (float*)alloc(64 * 4);
    int*   done     = (int*)alloc(64 * 4);
    int*   cnt      = (int*)alloc((size_t)N_NODES * 4);
    unsigned short* colu = (unsigned short*)alloc((size_t)N_NODES * CAP * 2);  // 4.8MB
    float* partial  = (float*)alloc((size_t)GATHER_BLOCKS * 256 * 4);          // 12.8MB
    int*   qcnt     = (int*)alloc((size_t)NPARTS * QSTRIDE * 4);               // 50KB padded
    // queue aliases partial (used strictly before the first gather writes partial)
    unsigned int* queue = (unsigned int*)partial;   // NPARTS*QCAP2*4 = 4.0MB <= 12.8MB
    const bool csr_ok = (ws_size >= off) || (ws_size == 0);
    float* colsum = stats;
    float* colsumsq = stats + 128;
    unsigned short* Bh = (unsigned short*)B;

    const int* srcv = ei;            // edge_index[0]
    const int* dstv = ei + N_EDGES;  // edge_index[1]

    const int PREP_BLOCKS = (3 * DIM * DIM + 3 * 3 * DIM + 255) / 256;
    prep<<<PREP_BLOCKS, 256, 0, stream>>>(
        (const unsigned short*)x, W, b, g, be, mode, Wt, pf32, qcnt, stats, done);

    if (csr_ok) {
        // LDS counting-sort binning (196 blocks, dispatched first) || layer-0 GEMM
        fused_a<<<BIN_BLOCKS + GEMM_BLOCKS, 256, 0, stream>>>(
            srcv, dstv, qcnt, queue, x, Wt, mode, hA);
        // phase B: per-part queues -> padded CSR + cnt + dinv
        csr_build<<<NPARTS, 256, 0, stream>>>(qcnt, queue, colu, cnt, dinv);

        for (int l = 0; l < 3; ++l) {
            if (l > 0)
                gemm_scale<<<GEMM_BLOCKS, 256, 0, stream>>>(
                    (const void*)B, 2, 1, Wt + (size_t)l * DIM * DIM, dinv, mode,
                    alphaB, deltaB, hA, B, 0);
            if (l == 0)
                gather_csr<1><<<GATHER_BLOCKS, 256, 0, stream>>>(
                    cnt, colu, hA, dinv, pf32 + l * 128, Bh, partial);
            else
                gather_csr<0><<<GATHER_BLOCKS, 256, 0, stream>>>(
                    cnt, colu, hA, dinv, pf32 + l * 128, Bh, partial);
            reduce_coefs<<<RED_BLOCKS, 256, 0, stream>>>(
                partial, stats, done, pf32, l, alphaB, deltaB);
            if (l == 2)
                bn_apply<<<(N_NODES * DIM) / 256, 256, 0, stream>>>(
                    (const void*)B, 1, dinv, alphaB, deltaB, mode, d_out);
        }
    } else {
        // fallback: original scatter pipeline (all layers use dinv-scaled gemm)
        zero_int<<<(N_NODES + 255) / 256, 256, 0, stream>>>(cnt, N_NODES);
        hist_dst<<<(N_EDGES + 255) / 256, 256, 0, stream>>>(dstv, cnt);
        make_dinv<<<(N_NODES + 255) / 256, 256, 0, stream>>>(cnt, dinv);

        for (int l = 0; l < 3; ++l) {
            const void* hin = (l == 0) ? x : (const void*)B;
            gemm_scale<<<GEMM_BLOCKS, 256, 0, stream>>>(
                hin, (l == 0) ? 0 : 2, 0, Wt + (size_t)l * DIM * DIM, dinv, mode,
                alphaB, deltaB, hA, B, 1);
            scatter_edges<<<(N_EDGES * 16) / 256, 256, 0, stream>>>(srcv, dstv, hA, B);
            bn_reduce<<<256, 256, 0, stream>>>(B, dinv, pf32 + l * 128, colsum, colsumsq);
            bn_coefs<<<1, 128, 0, stream>>>(pf32, l, colsum, colsumsq, alphaB, deltaB);
            if (l == 2)
                bn_apply<<<(N_NODES * DIM) / 256, 256, 0, stream>>>(
                    (const void*)B, 0, dinv, alphaB, deltaB, mode, d_out);
        }
    }
}

// Round 9
// 327.909 us; speedup vs baseline: 12.2070x; 1.0181x over previous
//
#include <hip/hip_runtime.h>
#include <hip/hip_bf16.h>

#define N_NODES 50000
#define N_EDGES 800000
#define DIM 128
#define BN_EPS 1e-5f
#define GATHER_BLOCKS (N_NODES / 4)           // 12500, 1 node per wave
#define RED_BLOCKS 125
#define CAP 48                                // padded CSR row capacity (actual max deg ~37)

// ---- CSR build constants (LDS counting-sort binning) ----
#define PART_SHIFT 7
#define PART_SIZE 128
#define NPARTS ((N_NODES + PART_SIZE - 1) / PART_SIZE)   // 391
#define QSTRIDE 32                                       // qcnt pad: 1 counter / 128B line
#define BIN_EPB 2048                                     // edges per binning block
#define BIN_BLOCKS ((N_EDGES + BIN_EPB - 1) / BIN_EPB)   // 391
#define QCAP2 2560                                       // per-part queue cap (mean 2046, +11 sigma)
#define GEMM_BLOCKS (N_NODES / 16)                       // 3125

typedef __attribute__((ext_vector_type(8))) short short8;
typedef __attribute__((ext_vector_type(4))) float float4v;

__device__ __forceinline__ float bf16_bits_to_f32(unsigned short u) {
    union { unsigned int i; float f; } c;
    c.i = ((unsigned int)u) << 16;
    return c.f;
}

__device__ __forceinline__ float bf16_lo(unsigned int u) {
    union { unsigned int i; float f; } c;
    c.i = u << 16;
    return c.f;
}

__device__ __forceinline__ float bf16_hi(unsigned int u) {
    union { unsigned int i; float f; } c;
    c.i = u & 0xFFFF0000u;
    return c.f;
}

__device__ __forceinline__ unsigned short f32_to_bf16_bits(float f) {
    union { float f; unsigned int i; } c;
    c.f = f;
    unsigned int lsb = (c.i >> 16) & 1u;
    c.i += 0x7FFFu + lsb;   // RNE
    return (unsigned short)(c.i >> 16);
}

// ---------------- zero-init helpers (fallback path) ----------------
__global__ __launch_bounds__(256) void zero_int(int* __restrict__ p, int n) {
    int i = blockIdx.x * blockDim.x + threadIdx.x;
    if (i < n) p[i] = 0;
}

// ---------------- prep: dtype sniff (per-block, local) + param convert + zeroing ----------------
__global__ __launch_bounds__(256) void prep(
    const unsigned short* __restrict__ xu,
    const void* __restrict__ W, const void* __restrict__ b,
    const void* __restrict__ g, const void* __restrict__ be,
    float* __restrict__ modeg, unsigned short* __restrict__ Wt,
    float* __restrict__ pf32,
    int* __restrict__ qcnt, float* __restrict__ stats, int* __restrict__ done) {
    __shared__ int okc;
    if (threadIdx.x == 0) okc = 0;
    __syncthreads();
    int ok = 0;
    for (int i = threadIdx.x; i < 512; i += 256) {
        unsigned e = (xu[i] >> 7) & 0xFFu;
        if (e >= 96u && e <= 159u) ok++;
    }
    atomicAdd(&okc, ok);
    __syncthreads();
    const bool mf32 = okc < 480;   // >=480 -> bf16(0), else f32(1)

    if (blockIdx.x == 0) {
        if (threadIdx.x == 0) { modeg[0] = mf32 ? 1.0f : 0.0f; done[0] = 0; done[1] = 0; }
        for (int i = threadIdx.x; i < NPARTS; i += 256) qcnt[(size_t)i * QSTRIDE] = 0;
        stats[threadIdx.x] = 0.0f;
    }

    int i = blockIdx.x * 256 + threadIdx.x;
    const int NW = 3 * DIM * DIM;  // 49152
    if (i < NW) {
        int l = i >> 14;
        int rem = i & 16383;
        int k = rem >> 7;
        int n = rem & 127;
        unsigned short v = mf32 ? f32_to_bf16_bits(((const float*)W)[i])
                                : ((const unsigned short*)W)[i];
        Wt[(size_t)l * DIM * DIM + (size_t)n * DIM + k] = v;  // transposed
    } else if (i < NW + 3 * 3 * DIM) {
        int p = i - NW;
        int which = p / 384;         // 0=b 1=gamma 2=beta
        int r = p - which * 384;
        const void* srcp = (which == 0) ? b : (which == 1) ? g : be;
        float v = mf32 ? ((const float*)srcp)[r]
                       : bf16_bits_to_f32(((const unsigned short*)srcp)[r]);
        pf32[which * 384 + r] = v;
    }
}

// ---------------- fused: LDS counting-sort binning (391 blocks) || layer-0 GEMM ----------------
// BIN_EPB 2048: binning blocks are the kernel's tail (4 barrier-separated passes);
// halving per-block work doubles parallelism. LDS ~8.8KB.
__global__ __launch_bounds__(256) void fused_a(
    const int* __restrict__ src, const int* __restrict__ dst,
    int* __restrict__ qcnt, unsigned int* __restrict__ queue,
    const void* __restrict__ x, const unsigned short* __restrict__ Wt,
    const float* __restrict__ mode, unsigned short* __restrict__ A) {
    __shared__ int lcnt[NPARTS];
    __shared__ int loff[NPARTS];   // scan result, then working offsets for pass 2
    __shared__ int adj[NPARTS];    // gbase - pref
    __shared__ unsigned short staged16[BIN_EPB];  // part-sorted local edge ids (4KB)
    __shared__ int sortedN;
    const int bid = blockIdx.x;
    if (bid < BIN_BLOCKS) {
        const int t = threadIdx.x;
        const int blk0 = bid * BIN_EPB;
        const int nval = min(BIN_EPB, N_EDGES - blk0);
        for (int i = t; i < NPARTS; i += 256) lcnt[i] = 0;
        __syncthreads();
        // pass 1: count parts
        for (int li = t; li < nval; li += 256) {
            int d = dst[blk0 + li];
            if ((unsigned)d < (unsigned)N_NODES)
                atomicAdd(&lcnt[d >> PART_SHIFT], 1);
        }
        __syncthreads();
        // wave-0 exclusive prefix scan over NPARTS -> loff (shuffle-based)
        if (t < 64) {
            int base = 0;
            for (int c = 0; c < (NPARTS + 63) / 64; ++c) {
                int idx = c * 64 + t;
                int orig = (idx < NPARTS) ? lcnt[idx] : 0;
                int v = orig;
                #pragma unroll
                for (int o = 1; o < 64; o <<= 1) {
                    int up = __shfl_up(v, o);
                    if (t >= o) v += up;
                }
                if (idx < NPARTS) loff[idx] = base + v - orig;
                base += __shfl(v, 63);
            }
            if (t == 0) sortedN = base;
        }
        __syncthreads();
        // one global reservation per (block, part); adj = gbase - pref
        for (int i = t; i < NPARTS; i += 256) {
            int c = lcnt[i];
            int gb = c ? atomicAdd(&qcnt[(size_t)i * QSTRIDE], c) : 0;
            adj[i] = gb - loff[i];
        }
        __syncthreads();
        // pass 2: LDS sort local edge ids by part (dst re-read, L1-hot window)
        for (int li = t; li < nval; li += 256) {
            int d = dst[blk0 + li];
            if ((unsigned)d < (unsigned)N_NODES) {
                int part = d >> PART_SHIFT;
                int pos = atomicAdd(&loff[part], 1);
                staged16[pos] = (unsigned short)li;
            }
        }
        __syncthreads();
        // output: dense per-part runs; re-derive src/dst (both windows L1-resident)
        const int nOut = sortedN;
        for (int i = t; i < nOut; i += 256) {
            int li = staged16[i];
            int d = dst[blk0 + li];
            int s = src[blk0 + li];
            int part = d >> PART_SHIFT;
            int gp = adj[part] + i;
            if (gp >= 0 && gp < QCAP2)
                queue[(size_t)part * QCAP2 + gp] =
                    (unsigned int)(s & 0xFFFF) |
                    ((unsigned int)(d & (PART_SIZE - 1)) << 16);
        }
        return;
    }
    // ---- layer-0 GEMM (kind 0, unscaled output) ----
    const int wave = threadIdx.x >> 6;
    const int lane = threadIdx.x & 63;
    const int quad = lane >> 4;
    const int nidx = lane & 15;
    const int row0 = (bid - BIN_BLOCKS) * 16;

    short8 afrag[4];
    if (mode[0] > 0.5f) {
        const float* xf = (const float*)x;
        #pragma unroll
        for (int kk = 0; kk < 4; ++kk) {
            const float4v* xr = (const float4v*)(xf + (size_t)(row0 + nidx) * DIM + kk * 32 + quad * 8);
            float4v p0 = xr[0], p1 = xr[1];
            #pragma unroll
            for (int j = 0; j < 4; ++j) {
                afrag[kk][j]     = (short)f32_to_bf16_bits(p0[j]);
                afrag[kk][4 + j] = (short)f32_to_bf16_bits(p1[j]);
            }
        }
    } else {
        const unsigned short* hu = (const unsigned short*)x;
        #pragma unroll
        for (int kk = 0; kk < 4; ++kk)
            afrag[kk] = *(const short8*)(hu + (size_t)(row0 + nidx) * DIM + kk * 32 + quad * 8);
    }

    short8 bfrag[2][4];
    #pragma unroll
    for (int half = 0; half < 2; ++half) {
        int c = wave * 32 + half * 16 + nidx;
        #pragma unroll
        for (int kk = 0; kk < 4; ++kk)
            bfrag[half][kk] = *(const short8*)(Wt + (size_t)c * DIM + kk * 32 + quad * 8);
    }

    float4v acc0 = {0.f, 0.f, 0.f, 0.f};
    float4v acc1 = {0.f, 0.f, 0.f, 0.f};
    #pragma unroll
    for (int kk = 0; kk < 4; ++kk) {
        acc0 = __builtin_amdgcn_mfma_f32_16x16x32_bf16(afrag[kk], bfrag[0][kk], acc0, 0, 0, 0);
        acc1 = __builtin_amdgcn_mfma_f32_16x16x32_bf16(afrag[kk], bfrag[1][kk], acc1, 0, 0, 0);
    }

    #pragma unroll
    for (int r = 0; r < 4; ++r) {
        int row = row0 + quad * 4 + r;
        size_t i0 = (size_t)row * DIM + wave * 32 + nidx;
        A[i0]      = f32_to_bf16_bits(acc0[r]);
        A[i0 + 16] = f32_to_bf16_bits(acc1[r]);
    }
}

// ---------------- phase B: drain per-part queue -> padded CSR, LDS-atomic positions ----------------
__global__ __launch_bounds__(256) void csr_build(
    const int* __restrict__ qcnt, const unsigned int* __restrict__ queue,
    unsigned short* __restrict__ colu, int* __restrict__ cnt,
    float* __restrict__ dinv) {
    __shared__ int lcnt[PART_SIZE];
    const int p = blockIdx.x;                 // 0..NPARTS-1
    if (threadIdx.x < PART_SIZE) lcnt[threadIdx.x] = 0;
    __syncthreads();
    const int base = p << PART_SHIFT;
    const int n = min(qcnt[(size_t)p * QSTRIDE], QCAP2);
    const unsigned int* qp = queue + (size_t)p * QCAP2;
    for (int i = threadIdx.x; i < n; i += 256) {
        unsigned int pk = qp[i];
        int dl = (pk >> 16) & (PART_SIZE - 1);
        int s  = pk & 0xFFFFu;
        int pos = atomicAdd(&lcnt[dl], 1);
        if (pos < CAP)
            colu[(size_t)(base + dl) * CAP + pos] = (unsigned short)s;
    }
    __syncthreads();
    if (threadIdx.x < PART_SIZE) {
        int d = base + threadIdx.x;
        if (d < N_NODES) {
            int c = lcnt[threadIdx.x];
            cnt[d] = c;                               // true degree
            dinv[d] = rsqrtf((float)c + 1.0f);        // +1 self-loop
        }
    }
}

__global__ __launch_bounds__(256) void make_dinv(const int* __restrict__ cnt,
                                                 float* __restrict__ dinv) {
    int v = blockIdx.x * blockDim.x + threadIdx.x;
    if (v < N_NODES) dinv[v] = rsqrtf((float)cnt[v] + 1.0f);  // +1 self-loop
}

// ---------------- GEMM (MFMA): msg = dinv[row]*(h@W) ----------------
__global__ __launch_bounds__(256) void gemm_scale(
    const void* hsrc, int kind, int b_bf16,
    const unsigned short* __restrict__ Wt,
    const float* __restrict__ dinv,
    const float* __restrict__ mode,
    const float* __restrict__ alpha, const float* __restrict__ delta,
    unsigned short* A, float* __restrict__ B, int write_b) {
    const int wave = threadIdx.x >> 6;
    const int lane = threadIdx.x & 63;
    const int quad = lane >> 4;
    const int nidx = lane & 15;
    const int row0 = blockIdx.x * 16;

    short8 afrag[4];
    if (kind == 0) {
        if (mode[0] > 0.5f) {
            const float* xf = (const float*)hsrc;
            #pragma unroll
            for (int kk = 0; kk < 4; ++kk) {
                const float4v* xr = (const float4v*)(xf + (size_t)(row0 + nidx) * DIM + kk * 32 + quad * 8);
                float4v p0 = xr[0], p1 = xr[1];
                #pragma unroll
                for (int j = 0; j < 4; ++j) {
                    afrag[kk][j]     = (short)f32_to_bf16_bits(p0[j]);
                    afrag[kk][4 + j] = (short)f32_to_bf16_bits(p1[j]);
                }
            }
        } else {
            const unsigned short* hu = (const unsigned short*)hsrc;
            #pragma unroll
            for (int kk = 0; kk < 4; ++kk)
                afrag[kk] = *(const short8*)(hu + (size_t)(row0 + nidx) * DIM + kk * 32 + quad * 8);
        }
    } else if (b_bf16) {
        const unsigned short* Bh = (const unsigned short*)hsrc;
        const float dv = dinv[row0 + nidx];
        #pragma unroll
        for (int kk = 0; kk < 4; ++kk) {
            short8 braw = *(const short8*)(Bh + (size_t)(row0 + nidx) * DIM + kk * 32 + quad * 8);
            const float* ap = alpha + kk * 32 + quad * 8;
            const float* dp = delta + kk * 32 + quad * 8;
            float4v A0 = *(const float4v*)ap, A1 = *(const float4v*)(ap + 4);
            float4v D0 = *(const float4v*)dp, D1 = *(const float4v*)(dp + 4);
            #pragma unroll
            for (int j = 0; j < 4; ++j) {
                float v0 = bf16_bits_to_f32((unsigned short)braw[j]);
                float v1 = bf16_bits_to_f32((unsigned short)braw[4 + j]);
                float h0 = fmaxf(fmaf(A0[j] * dv, v0, D0[j]), 0.f);
                float h1 = fmaxf(fmaf(A1[j] * dv, v1, D1[j]), 0.f);
                afrag[kk][j]     = (short)f32_to_bf16_bits(h0);
                afrag[kk][4 + j] = (short)f32_to_bf16_bits(h1);
            }
        }
    } else {
        const float* Bf = (const float*)hsrc;
        const float dv = dinv[row0 + nidx];
        #pragma unroll
        for (int kk = 0; kk < 4; ++kk) {
            const float* bp = Bf + (size_t)(row0 + nidx) * DIM + kk * 32 + quad * 8;
            float4v p0 = *(const float4v*)bp;
            float4v p1 = *(const float4v*)(bp + 4);
            const float* ap = alpha + kk * 32 + quad * 8;
            const float* dp = delta + kk * 32 + quad * 8;
            float4v A0 = *(const float4v*)ap, A1 = *(const float4v*)(ap + 4);
            float4v D0 = *(const float4v*)dp, D1 = *(const float4v*)(dp + 4);
            #pragma unroll
            for (int j = 0; j < 4; ++j) {
                float h0 = fmaxf(fmaf(A0[j] * dv, p0[j], D0[j]), 0.f);
                float h1 = fmaxf(fmaf(A1[j] * dv, p1[j], D1[j]), 0.f);
                afrag[kk][j]     = (short)f32_to_bf16_bits(h0);
                afrag[kk][4 + j] = (short)f32_to_bf16_bits(h1);
            }
        }
    }

    short8 bfrag[2][4];
    #pragma unroll
    for (int half = 0; half < 2; ++half) {
        int c = wave * 32 + half * 16 + nidx;
        #pragma unroll
        for (int kk = 0; kk < 4; ++kk)
            bfrag[half][kk] = *(const short8*)(Wt + (size_t)c * DIM + kk * 32 + quad * 8);
    }

    float4v acc0 = {0.f, 0.f, 0.f, 0.f};
    float4v acc1 = {0.f, 0.f, 0.f, 0.f};
    #pragma unroll
    for (int kk = 0; kk < 4; ++kk) {
        acc0 = __builtin_amdgcn_mfma_f32_16x16x32_bf16(afrag[kk], bfrag[0][kk], acc0, 0, 0, 0);
        acc1 = __builtin_amdgcn_mfma_f32_16x16x32_bf16(afrag[kk], bfrag[1][kk], acc1, 0, 0, 0);
    }

    #pragma unroll
    for (int r = 0; r < 4; ++r) {
        int row = row0 + quad * 4 + r;
        float d = dinv[row];
        float v0 = acc0[r] * d;
        float v1 = acc1[r] * d;
        size_t i0 = (size_t)row * DIM + wave * 32 + nidx;
        size_t i1 = i0 + 16;
        A[i0] = f32_to_bf16_bits(v0);
        A[i1] = f32_to_bf16_bits(v1);
        if (write_b) { B[i0] = v0; B[i1] = v1; }
    }
}

// ---------------- padded-CSR gather v3.1 + fused BN stats (NO device fences here!) ----------------
// 1 node/wave, 16 lanes/edge x 16B: one wave-inst loads 4 full edge-rows. Chunk 0 is
// UNGUARDED (cv=0,w=0 padding makes OOB loads safe: row 0, weight 0 — valid even for
// deg=0); chunks 1,2 guarded by wave-uniform deg (divergence-free).
#define FMA8(vv, ww) do { \
    a0 = fmaf(ww, bf16_lo(vv.x), a0); a1 = fmaf(ww, bf16_hi(vv.x), a1); \
    a2 = fmaf(ww, bf16_lo(vv.y), a2); a3 = fmaf(ww, bf16_hi(vv.y), a3); \
    a4 = fmaf(ww, bf16_lo(vv.z), a4); a5 = fmaf(ww, bf16_hi(vv.z), a5); \
    a6 = fmaf(ww, bf16_lo(vv.w), a6); a7 = fmaf(ww, bf16_hi(vv.w), a7); } while (0)

#define CHUNK16(jbase) do { \
    int i0 = (jbase) + g, i1 = (jbase) + 4 + g, i2 = (jbase) + 8 + g, i3 = (jbase) + 12 + g; \
    int   s0 = __shfl(cv, i0);  float w0 = __shfl(wv, i0); \
    int   s1 = __shfl(cv, i1);  float w1 = __shfl(wv, i1); \
    int   s2 = __shfl(cv, i2);  float w2 = __shfl(wv, i2); \
    int   s3 = __shfl(cv, i3);  float w3 = __shfl(wv, i3); \
    uint4 v0 = *(const uint4*)(A + (size_t)s0 * DIM + c8); \
    uint4 v1 = *(const uint4*)(A + (size_t)s1 * DIM + c8); \
    uint4 v2 = *(const uint4*)(A + (size_t)s2 * DIM + c8); \
    uint4 v3 = *(const uint4*)(A + (size_t)s3 * DIM + c8); \
    FMA8(v0, w0); FMA8(v1, w1); FMA8(v2, w2); FMA8(v3, w3); } while (0)

template <int SC>
__global__ __launch_bounds__(256) void gather_csr(
    const int* __restrict__ cnt, const unsigned short* __restrict__ colu,
    const unsigned short* __restrict__ A,
    const float* __restrict__ dinv, const float* __restrict__ bias,
    unsigned short* __restrict__ Bh, float* __restrict__ partial) {
    __shared__ float sacc[4][128], sacc2[4][128];
    const int wave = threadIdx.x >> 6;
    const int lane = threadIdx.x & 63;
    const int g    = lane >> 4;        // edge slot within a 4-edge chunk
    const int c8   = (lane & 15) * 8;  // 8 columns (16B) per lane
    const int node = blockIdx.x * 4 + wave;   // exact: 12500*4 = 50000
    const int deg  = min(cnt[node], CAP);
    const int lo   = node * CAP;
    const float dv = dinv[node];

    // preload edge list + weights into per-lane registers (one coalesced pass)
    int   cv = (lane < deg) ? (int)colu[lo + lane] : 0;
    float wv = (lane < deg) ? (SC ? dinv[cv] : 1.0f) : 0.0f;

    // init accumulators with self-loop term (counted once via group 0)
    float a0, a1, a2, a3, a4, a5, a6, a7;
    {
        uint4 sv = *(const uint4*)(A + (size_t)node * DIM + c8);
        const float scl = (g == 0) ? (SC ? dv : 1.0f) : 0.0f;
        a0 = scl * bf16_lo(sv.x); a1 = scl * bf16_hi(sv.x);
        a2 = scl * bf16_lo(sv.y); a3 = scl * bf16_hi(sv.y);
        a4 = scl * bf16_lo(sv.z); a5 = scl * bf16_hi(sv.z);
        a6 = scl * bf16_lo(sv.w); a7 = scl * bf16_hi(sv.w);
    }

    CHUNK16(0);                       // unguarded: safe via zero-weight padding
    if (16 < deg) CHUNK16(16);        // wave-uniform guard
    if (32 < deg) CHUNK16(32);

    // reduce across the 4 edge-groups (lane bits 4,5)
    a0 += __shfl_xor(a0, 16); a0 += __shfl_xor(a0, 32);
    a1 += __shfl_xor(a1, 16); a1 += __shfl_xor(a1, 32);
    a2 += __shfl_xor(a2, 16); a2 += __shfl_xor(a2, 32);
    a3 += __shfl_xor(a3, 16); a3 += __shfl_xor(a3, 32);
    a4 += __shfl_xor(a4, 16); a4 += __shfl_xor(a4, 32);
    a5 += __shfl_xor(a5, 16); a5 += __shfl_xor(a5, 32);
    a6 += __shfl_xor(a6, 16); a6 += __shfl_xor(a6, 32);
    a7 += __shfl_xor(a7, 16); a7 += __shfl_xor(a7, 32);

    if (lane < 16) {
        unsigned int p0 = (unsigned int)f32_to_bf16_bits(a0) | ((unsigned int)f32_to_bf16_bits(a1) << 16);
        unsigned int p1 = (unsigned int)f32_to_bf16_bits(a2) | ((unsigned int)f32_to_bf16_bits(a3) << 16);
        unsigned int p2 = (unsigned int)f32_to_bf16_bits(a4) | ((unsigned int)f32_to_bf16_bits(a5) << 16);
        unsigned int p3 = (unsigned int)f32_to_bf16_bits(a6) | ((unsigned int)f32_to_bf16_bits(a7) << 16);
        uint4 st = {p0, p1, p2, p3};
        *(uint4*)(Bh + (size_t)node * DIM + c8) = st;
        float4 b0 = *(const float4*)(bias + c8);
        float4 b1 = *(const float4*)(bias + c8 + 4);
        float v0 = fmaf(dv, a0, b0.x), v1 = fmaf(dv, a1, b0.y);
        float v2 = fmaf(dv, a2, b0.z), v3 = fmaf(dv, a3, b0.w);
        float v4 = fmaf(dv, a4, b1.x), v5 = fmaf(dv, a5, b1.y);
        float v6 = fmaf(dv, a6, b1.z), v7 = fmaf(dv, a7, b1.w);
        sacc[wave][c8]     = v0;  sacc2[wave][c8]     = v0 * v0;
        sacc[wave][c8 + 1] = v1;  sacc2[wave][c8 + 1] = v1 * v1;
        sacc[wave][c8 + 2] = v2;  sacc2[wave][c8 + 2] = v2 * v2;
        sacc[wave][c8 + 3] = v3;  sacc2[wave][c8 + 3] = v3 * v3;
        sacc[wave][c8 + 4] = v4;  sacc2[wave][c8 + 4] = v4 * v4;
        sacc[wave][c8 + 5] = v5;  sacc2[wave][c8 + 5] = v5 * v5;
        sacc[wave][c8 + 6] = v6;  sacc2[wave][c8 + 6] = v6 * v6;
        sacc[wave][c8 + 7] = v7;  sacc2[wave][c8 + 7] = v7 * v7;
    }
    __syncthreads();
    const int t = threadIdx.x;
    float s;
    if (t < 128) s = sacc[0][t] + sacc[1][t] + sacc[2][t] + sacc[3][t];
    else { int c = t - 128; s = sacc2[0][c] + sacc2[1][c] + sacc2[2][c] + sacc2[3][c]; }
    partial[(size_t)blockIdx.x * 256 + t] = s;   // coalesced, no atomics
}

// ---------------- reduce partials -> stats, last block computes BN coefs ----------------
// Device fences are confined to this NARROW kernel (125 blocks) — cheap.
__global__ __launch_bounds__(256) void reduce_coefs(
    const float* __restrict__ partial, float* __restrict__ stats,
    int* __restrict__ done, const float* __restrict__ pf32, int l,
    float* __restrict__ alpha, float* __restrict__ delta) {
    const int t = threadIdx.x;
    const int rows = GATHER_BLOCKS / RED_BLOCKS;   // 100
    const int r0 = blockIdx.x * rows;
    float s = 0.f;
    for (int i = 0; i < rows; ++i)
        s += partial[(size_t)(r0 + i) * 256 + t];
    atomicAdd(&stats[t], s);
    __threadfence();
    __shared__ int lastFlag;
    if (t == 0) lastFlag = (atomicAdd(done, 1) == RED_BLOCKS - 1) ? 1 : 0;
    __syncthreads();
    if (lastFlag && t < 128) {
        float cs  = atomicAdd(&stats[t], 0.0f);
        float css = atomicAdd(&stats[t + 128], 0.0f);
        const float invN = 1.0f / N_NODES;
        float mu = cs * invN;
        float var = css * invN - mu * mu;
        float istd = rsqrtf(var + BN_EPS);
        float gg = pf32[384 + l * 128 + t];
        float bt = pf32[768 + l * 128 + t];
        float bi = pf32[l * 128 + t];
        float al = gg * istd;
        alpha[t] = al;
        delta[t] = al * (bi - mu) + bt;
        atomicExch(&stats[t], 0.0f);
        atomicExch(&stats[t + 128], 0.0f);
        if (t == 0) atomicExch(done, 0);
    }
}

// ---------------- BN coefs (fallback path only) ----------------
__global__ __launch_bounds__(128) void bn_coefs(
    const float* __restrict__ pf32, int l,
    float* __restrict__ colsum, float* __restrict__ colsumsq,
    float* __restrict__ alpha, float* __restrict__ delta) {
    int c = threadIdx.x;
    const float invN = 1.0f / N_NODES;
    float mu = colsum[c] * invN;
    float var = colsumsq[c] * invN - mu * mu;
    float istd = rsqrtf(var + BN_EPS);
    float gg = pf32[384 + l * 128 + c];
    float bt = pf32[768 + l * 128 + c];
    float bi = pf32[l * 128 + c];
    float al = gg * istd;
    alpha[c] = al;
    delta[c] = al * (bi - mu) + bt;
    colsum[c] = 0.f;
    colsumsq[c] = 0.f;
}

// ---------------- fallback path (ws too small): hist + scatter + bn_reduce ----------------
__global__ __launch_bounds__(256) void hist_dst(const int* __restrict__ dst,
                                                int* __restrict__ cnt) {
    int e = blockIdx.x * blockDim.x + threadIdx.x;
    if (e < N_EDGES) atomicAdd(&cnt[dst[e]], 1);
}

__global__ __launch_bounds__(256) void scatter_edges(
    const int* __restrict__ src, const int* __restrict__ dst,
    const unsigned short* __restrict__ A, float* __restrict__ B) {
    int t = blockIdx.x * blockDim.x + threadIdx.x;
    int e = t >> 4;
    if (e >= N_EDGES) return;
    int f = (t & 15) * 8;
    int s = src[e], d = dst[e];
    short8 v = *(const short8*)(A + (size_t)s * DIM + f);
    float* bp = B + (size_t)d * DIM + f;
    #pragma unroll
    for (int j = 0; j < 8; ++j)
        atomicAdd(bp + j, bf16_bits_to_f32((unsigned short)v[j]));
}

__global__ __launch_bounds__(256) void bn_reduce(
    const float* __restrict__ B, const float* __restrict__ dinv,
    const float* __restrict__ bias,
    float* __restrict__ colsum, float* __restrict__ colsumsq) {
    int c = threadIdx.x & 127;
    int half = threadIdx.x >> 7;
    float bb = bias[c];
    float s = 0.f, s2 = 0.f;
    for (int row = blockIdx.x * 2 + half; row < N_NODES; row += gridDim.x * 2) {
        float v = dinv[row] * B[(size_t)row * DIM + c] + bb;
        s += v;
        s2 += v * v;
    }
    __shared__ float ls[128], ls2[128];
    if (half == 1) { ls[c] = s; ls2[c] = s2; }
    __syncthreads();
    if (half == 0) {
        atomicAdd(&colsum[c], s + ls[c]);
        atomicAdd(&colsumsq[c], s2 + ls2[c]);
    }
}

// ---------------- final output: BN apply + ReLU, 8 elems/thread (vectorized) ----------------
__global__ __launch_bounds__(256) void bn_apply(
    const void* __restrict__ Bv, int b_bf16,
    const float* __restrict__ dinv,
    const float* __restrict__ alpha, const float* __restrict__ delta,
    const float* __restrict__ mode, void* __restrict__ out) {
    int t = blockIdx.x * blockDim.x + threadIdx.x;   // one thread = 8 elems
    if (t >= N_NODES * DIM / 8) return;
    int row = t >> 4;              // 16 threads per row
    int c8  = (t & 15) * 8;
    float dv = dinv[row];
    float4 A0 = *(const float4*)(alpha + c8), A1 = *(const float4*)(alpha + c8 + 4);
    float4 D0 = *(const float4*)(delta + c8), D1 = *(const float4*)(delta + c8 + 4);
    float v[8];
    if (b_bf16) {
        uint4 bv = *(const uint4*)((const unsigned short*)Bv + (size_t)row * DIM + c8);
        v[0] = bf16_lo(bv.x); v[1] = bf16_hi(bv.x);
        v[2] = bf16_lo(bv.y); v[3] = bf16_hi(bv.y);
        v[4] = bf16_lo(bv.z); v[5] = bf16_hi(bv.z);
        v[6] = bf16_lo(bv.w); v[7] = bf16_hi(bv.w);
    } else {
        const float* bf = (const float*)Bv + (size_t)row * DIM + c8;
        #pragma unroll
        for (int j = 0; j < 8; ++j) v[j] = bf[j];
    }
    float al[8] = {A0.x, A0.y, A0.z, A0.w, A1.x, A1.y, A1.z, A1.w};
    float de[8] = {D0.x, D0.y, D0.z, D0.w, D1.x, D1.y, D1.z, D1.w};
    float r[8];
    #pragma unroll
    for (int j = 0; j < 8; ++j)
        r[j] = fmaxf(fmaf(al[j] * dv, v[j], de[j]), 0.f);
    if (mode[0] > 0.5f) {
        float4* op = (float4*)((float*)out + (size_t)row * DIM + c8);
        float4 o0 = {r[0], r[1], r[2], r[3]};
        float4 o1 = {r[4], r[5], r[6], r[7]};
        op[0] = o0; op[1] = o1;
    } else {
        unsigned int p0 = (unsigned int)f32_to_bf16_bits(r[0]) | ((unsigned int)f32_to_bf16_bits(r[1]) << 16);
        unsigned int p1 = (unsigned int)f32_to_bf16_bits(r[2]) | ((unsigned int)f32_to_bf16_bits(r[3]) << 16);
        unsigned int p2 = (unsigned int)f32_to_bf16_bits(r[4]) | ((unsigned int)f32_to_bf16_bits(r[5]) << 16);
        unsigned int p3 = (unsigned int)f32_to_bf16_bits(r[6]) | ((unsigned int)f32_to_bf16_bits(r[7]) << 16);
        uint4 st = {p0, p1, p2, p3};
        *(uint4*)((unsigned short*)out + (size_t)row * DIM + c8) = st;
    }
}

extern "C" void kernel_launch(void* const* d_in, const int* in_sizes, int n_in,
                              void* d_out, int out_size, void* d_ws, size_t ws_size,
                              hipStream_t stream) {
    const void* x  = d_in[0];
    const int*  ei = (const int*)d_in[1];
    const void* W  = d_in[2];
    const void* b  = d_in[3];
    const void* g  = d_in[4];
    const void* be = d_in[5];

    unsigned short* hA = (unsigned short*)d_out;  // bf16 message buffer

    char* ws = (char*)d_ws;
    size_t off = 0;
    auto alloc = [&](size_t bytes) {
        char* p = ws + off;
        off = (off + bytes + 255) & ~(size_t)255;
        return p;
    };
    float* dinv     = (float*)alloc((size_t)N_NODES * 4);
    float* B        = (float*)alloc((size_t)N_NODES * DIM * 4);  // f32 for fallback; CSR uses as bf16
    unsigned short* Wt = (unsigned short*)alloc((size_t)3 * DIM * DIM * 2);
    float* pf32     = (float*)alloc(3 * 3 * DIM * 4);
    float* stats    = (float*)alloc(256 * 4);   // colsum[0:128] || colsumsq[128:256]
    float* alphaB   = (float*)alloc(128 * 4);
    float* deltaB   = (float*)alloc(128 * 4);
    float* mode     = (float*)alloc(64 * 4);
    int*   done     = (int*)alloc(64 * 4);
    int*   cnt      = (int*)alloc((size_t)N_NODES * 4);
    unsigned short* colu = (unsigned short*)alloc((size_t)N_NODES * CAP * 2);  // 4.8MB
    float* partial  = (float*)alloc((size_t)GATHER_BLOCKS * 256 * 4);          // 12.8MB
    int*   qcnt     = (int*)alloc((size_t)NPARTS * QSTRIDE * 4);               // 50KB padded
    // queue aliases partial (used strictly before the first gather writes partial)
    unsigned int* queue = (unsigned int*)partial;   // NPARTS*QCAP2*4 = 4.0MB <= 12.8MB
    const bool csr_ok = (ws_size >= off) || (ws_size == 0);
    float* colsum = stats;
    float* colsumsq = stats + 128;
    unsigned short* Bh = (unsigned short*)B;

    const int* srcv = ei;            // edge_index[0]
    const int* dstv = ei + N_EDGES;  // edge_index[1]

    const int PREP_BLOCKS = (3 * DIM * DIM + 3 * 3 * DIM + 255) / 256;
    prep<<<PREP_BLOCKS, 256, 0, stream>>>(
        (const unsigned short*)x, W, b, g, be, mode, Wt, pf32, qcnt, stats, done);

    if (csr_ok) {
        // LDS counting-sort binning (391 blocks, dispatched first) || layer-0 GEMM
        fused_a<<<BIN_BLOCKS + GEMM_BLOCKS, 256, 0, stream>>>(
            srcv, dstv, qcnt, queue, x, Wt, mode, hA);
        // phase B: per-part queues -> padded CSR + cnt + dinv
        csr_build<<<NPARTS, 256, 0, stream>>>(qcnt, queue, colu, cnt, dinv);

        for (int l = 0; l < 3; ++l) {
            if (l > 0)
                gemm_scale<<<GEMM_BLOCKS, 256, 0, stream>>>(
                    (const void*)B, 2, 1, Wt + (size_t)l * DIM * DIM, dinv, mode,
                    alphaB, deltaB, hA, B, 0);
            if (l == 0)
                gather_csr<1><<<GATHER_BLOCKS, 256, 0, stream>>>(
                    cnt, colu, hA, dinv, pf32 + l * 128, Bh, partial);
            else
                gather_csr<0><<<GATHER_BLOCKS, 256, 0, stream>>>(
                    cnt, colu, hA, dinv, pf32 + l * 128, Bh, partial);
            reduce_coefs<<<RED_BLOCKS, 256, 0, stream>>>(
                partial, stats, done, pf32, l, alphaB, deltaB);
            if (l == 2)
                bn_apply<<<(N_NODES * DIM / 8 + 255) / 256, 256, 0, stream>>>(
                    (const void*)B, 1, dinv, alphaB, deltaB, mode, d_out);
        }
    } else {
        // fallback: original scatter pipeline (all layers use dinv-scaled gemm)
        zero_int<<<(N_NODES + 255) / 256, 256, 0, stream>>>(cnt, N_NODES);
        hist_dst<<<(N_EDGES + 255) / 256, 256, 0, stream>>>(dstv, cnt);
        make_dinv<<<(N_NODES + 255) / 256, 256, 0, stream>>>(cnt, dinv);

        for (int l = 0; l < 3; ++l) {
            const void* hin = (l == 0) ? x : (const void*)B;
            gemm_scale<<<GEMM_BLOCKS, 256, 0, stream>>>(
                hin, (l == 0) ? 0 : 2, 0, Wt + (size_t)l * DIM * DIM, dinv, mode,
                alphaB, deltaB, hA, B, 1);
            scatter_edges<<<(N_EDGES * 16) / 256, 256, 0, stream>>>(srcv, dstv, hA, B);
            bn_reduce<<<256, 256, 0, stream>>>(B, dinv, pf32 + l * 128, colsum, colsumsq);
            bn_coefs<<<1, 128, 0, stream>>>(pf32, l, colsum, colsumsq, alphaB, deltaB);
            if (l == 2)
                bn_apply<<<(N_NODES * DIM / 8 + 255) / 256, 256, 0, stream>>>(
                    (const void*)B, 0, dinv, alphaB, deltaB, mode, d_out);
        }
    }
}

// Round 10
// 315.398 us; speedup vs baseline: 12.6912x; 1.0397x over previous
//
#include <hip/hip_runtime.h>
#include <hip/hip_bf16.h>

#define N_NODES 50000
#define N_EDGES 800000
#define DIM 128
#define BN_EPS 1e-5f
#define GATHER_BLOCKS (N_NODES / 4)           // 12500, 1 node per wave
#define RED_BLOCKS 125
#define CAP 48                                // padded CSR row capacity (actual max deg ~37)

// ---- CSR build constants (LDS counting binning, direct-write) ----
#define PART_SHIFT 7
#define PART_SIZE 128
#define NPARTS ((N_NODES + PART_SIZE - 1) / PART_SIZE)   // 391
#define QSTRIDE 32                                       // qcnt pad: 1 counter / 128B line
#define BIN_EPB 2048                                     // edges per binning block
#define BIN_BLOCKS ((N_EDGES + BIN_EPB - 1) / BIN_EPB)   // 391
#define QCAP2 2560                                       // per-part queue cap (mean 2046, +11 sigma)
#define GEMM_BLOCKS ((N_NODES + 31) / 32)                // 1563 (32 rows/block, r9)

typedef __attribute__((ext_vector_type(8))) short short8;
typedef __attribute__((ext_vector_type(4))) float float4v;

__device__ __forceinline__ float bf16_bits_to_f32(unsigned short u) {
    union { unsigned int i; float f; } c;
    c.i = ((unsigned int)u) << 16;
    return c.f;
}

__device__ __forceinline__ float bf16_lo(unsigned int u) {
    union { unsigned int i; float f; } c;
    c.i = u << 16;
    return c.f;
}

__device__ __forceinline__ float bf16_hi(unsigned int u) {
    union { unsigned int i; float f; } c;
    c.i = u & 0xFFFF0000u;
    return c.f;
}

__device__ __forceinline__ unsigned short f32_to_bf16_bits(float f) {
    union { float f; unsigned int i; } c;
    c.f = f;
    unsigned int lsb = (c.i >> 16) & 1u;
    c.i += 0x7FFFu + lsb;   // RNE
    return (unsigned short)(c.i >> 16);
}

// ---------------- zero-init helpers (fallback path) ----------------
__global__ __launch_bounds__(256) void zero_int(int* __restrict__ p, int n) {
    int i = blockIdx.x * blockDim.x + threadIdx.x;
    if (i < n) p[i] = 0;
}

// ---------------- prep: dtype sniff (per-block, local) + param convert + zeroing ----------------
__global__ __launch_bounds__(256) void prep(
    const unsigned short* __restrict__ xu,
    const void* __restrict__ W, const void* __restrict__ b,
    const void* __restrict__ g, const void* __restrict__ be,
    float* __restrict__ modeg, unsigned short* __restrict__ Wt,
    float* __restrict__ pf32,
    int* __restrict__ qcnt, float* __restrict__ stats, int* __restrict__ done) {
    __shared__ int okc;
    if (threadIdx.x == 0) okc = 0;
    __syncthreads();
    int ok = 0;
    for (int i = threadIdx.x; i < 512; i += 256) {
        unsigned e = (xu[i] >> 7) & 0xFFu;
        if (e >= 96u && e <= 159u) ok++;
    }
    atomicAdd(&okc, ok);
    __syncthreads();
    const bool mf32 = okc < 480;   // >=480 -> bf16(0), else f32(1)

    if (blockIdx.x == 0) {
        if (threadIdx.x == 0) { modeg[0] = mf32 ? 1.0f : 0.0f; done[0] = 0; done[1] = 0; }
        for (int i = threadIdx.x; i < NPARTS; i += 256) qcnt[(size_t)i * QSTRIDE] = 0;
        stats[threadIdx.x] = 0.0f;
    }

    int i = blockIdx.x * 256 + threadIdx.x;
    const int NW = 3 * DIM * DIM;  // 49152
    if (i < NW) {
        int l = i >> 14;
        int rem = i & 16383;
        int k = rem >> 7;
        int n = rem & 127;
        unsigned short v = mf32 ? f32_to_bf16_bits(((const float*)W)[i])
                                : ((const unsigned short*)W)[i];
        Wt[(size_t)l * DIM * DIM + (size_t)n * DIM + k] = v;  // transposed
    } else if (i < NW + 3 * 3 * DIM) {
        int p = i - NW;
        int which = p / 384;         // 0=b 1=gamma 2=beta
        int r = p - which * 384;
        const void* srcp = (which == 0) ? b : (which == 1) ? g : be;
        float v = mf32 ? ((const float*)srcp)[r]
                       : bf16_bits_to_f32(((const unsigned short*)srcp)[r]);
        pf32[which * 384 + r] = v;
    }
}

// ---------------- fused: LDS counting binning (391 blocks, direct-write) || layer-0 GEMM ----------------
// r9: staged16 sort REMOVED. Dense per-part runs come from the per-(block,part)
// reservation [gbase, gbase+c), not the staging — direct-write in pass 2 gives the
// identical write pattern. Binning: zero -> count -> reserve -> write (3 barriers,
// ~3.1KB LDS). GEMM: 32 rows/block, bfrag loaded ONCE and reused for 2 row-tiles
// (halves Wt L2 traffic; block count 3125 -> 1563).
__global__ __launch_bounds__(256) void fused_a(
    const int* __restrict__ src, const int* __restrict__ dst,
    int* __restrict__ qcnt, unsigned int* __restrict__ queue,
    const void* __restrict__ x, const unsigned short* __restrict__ Wt,
    const float* __restrict__ mode, unsigned short* __restrict__ A) {
    __shared__ int lcnt[NPARTS];
    __shared__ int loff[NPARTS];   // reservation base, then running write cursor
    const int bid = blockIdx.x;
    if (bid < BIN_BLOCKS) {
        const int t = threadIdx.x;
        const int blk0 = bid * BIN_EPB;
        const int nval = min(BIN_EPB, N_EDGES - blk0);
        for (int i = t; i < NPARTS; i += 256) lcnt[i] = 0;
        __syncthreads();
        // pass 1: count parts
        for (int li = t; li < nval; li += 256) {
            int d = dst[blk0 + li];
            if ((unsigned)d < (unsigned)N_NODES)
                atomicAdd(&lcnt[d >> PART_SHIFT], 1);
        }
        __syncthreads();
        // reserve: one global atomic per (block, part); loff = gbase
        for (int i = t; i < NPARTS; i += 256) {
            int c = lcnt[i];
            loff[i] = c ? atomicAdd(&qcnt[(size_t)i * QSTRIDE], c) : 0;
        }
        __syncthreads();
        // pass 2: direct dense-run write (dst/src windows L1-hot)
        for (int li = t; li < nval; li += 256) {
            int d = dst[blk0 + li];
            if ((unsigned)d < (unsigned)N_NODES) {
                int s = src[blk0 + li];
                int part = d >> PART_SHIFT;
                int pos = atomicAdd(&loff[part], 1);   // absolute queue index
                if (pos < QCAP2)
                    queue[(size_t)part * QCAP2 + pos] =
                        (unsigned int)(s & 0xFFFF) |
                        ((unsigned int)(d & (PART_SIZE - 1)) << 16);
            }
        }
        return;
    }
    // ---- layer-0 GEMM (kind 0, unscaled output), 32 rows/block, bfrag reused ----
    const int wave = threadIdx.x >> 6;
    const int lane = threadIdx.x & 63;
    const int quad = lane >> 4;
    const int nidx = lane & 15;
    const int row0 = (bid - BIN_BLOCKS) * 32;
    const bool mf = mode[0] > 0.5f;

    short8 bfrag[2][4];
    #pragma unroll
    for (int half = 0; half < 2; ++half) {
        int c = wave * 32 + half * 16 + nidx;
        #pragma unroll
        for (int kk = 0; kk < 4; ++kk)
            bfrag[half][kk] = *(const short8*)(Wt + (size_t)c * DIM + kk * 32 + quad * 8);
    }

    #pragma unroll
    for (int tile = 0; tile < 2; ++tile) {
        const int rt = row0 + tile * 16;
        if (rt >= N_NODES) break;               // block-uniform guard (tail block only)
        short8 afrag[4];
        if (mf) {
            const float* xf = (const float*)x;
            #pragma unroll
            for (int kk = 0; kk < 4; ++kk) {
                const float4v* xr = (const float4v*)(xf + (size_t)(rt + nidx) * DIM + kk * 32 + quad * 8);
                float4v p0 = xr[0], p1 = xr[1];
                #pragma unroll
                for (int j = 0; j < 4; ++j) {
                    afrag[kk][j]     = (short)f32_to_bf16_bits(p0[j]);
                    afrag[kk][4 + j] = (short)f32_to_bf16_bits(p1[j]);
                }
            }
        } else {
            const unsigned short* hu = (const unsigned short*)x;
            #pragma unroll
            for (int kk = 0; kk < 4; ++kk)
                afrag[kk] = *(const short8*)(hu + (size_t)(rt + nidx) * DIM + kk * 32 + quad * 8);
        }

        float4v acc0 = {0.f, 0.f, 0.f, 0.f};
        float4v acc1 = {0.f, 0.f, 0.f, 0.f};
        #pragma unroll
        for (int kk = 0; kk < 4; ++kk) {
            acc0 = __builtin_amdgcn_mfma_f32_16x16x32_bf16(afrag[kk], bfrag[0][kk], acc0, 0, 0, 0);
            acc1 = __builtin_amdgcn_mfma_f32_16x16x32_bf16(afrag[kk], bfrag[1][kk], acc1, 0, 0, 0);
        }

        #pragma unroll
        for (int r = 0; r < 4; ++r) {
            int row = rt + quad * 4 + r;
            size_t i0 = (size_t)row * DIM + wave * 32 + nidx;
            A[i0]      = f32_to_bf16_bits(acc0[r]);
            A[i0 + 16] = f32_to_bf16_bits(acc1[r]);
        }
    }
}

// ---------------- phase B: drain per-part queue -> padded CSR, LDS-atomic positions ----------------
__global__ __launch_bounds__(256) void csr_build(
    const int* __restrict__ qcnt, const unsigned int* __restrict__ queue,
    unsigned short* __restrict__ colu, int* __restrict__ cnt,
    float* __restrict__ dinv) {
    __shared__ int lcnt[PART_SIZE];
    const int p = blockIdx.x;                 // 0..NPARTS-1
    if (threadIdx.x < PART_SIZE) lcnt[threadIdx.x] = 0;
    __syncthreads();
    const int base = p << PART_SHIFT;
    const int n = min(qcnt[(size_t)p * QSTRIDE], QCAP2);
    const unsigned int* qp = queue + (size_t)p * QCAP2;
    for (int i = threadIdx.x; i < n; i += 256) {
        unsigned int pk = qp[i];
        int dl = (pk >> 16) & (PART_SIZE - 1);
        int s  = pk & 0xFFFFu;
        int pos = atomicAdd(&lcnt[dl], 1);
        if (pos < CAP)
            colu[(size_t)(base + dl) * CAP + pos] = (unsigned short)s;
    }
    __syncthreads();
    if (threadIdx.x < PART_SIZE) {
        int d = base + threadIdx.x;
        if (d < N_NODES) {
            int c = lcnt[threadIdx.x];
            cnt[d] = c;                               // true degree
            dinv[d] = rsqrtf((float)c + 1.0f);        // +1 self-loop
        }
    }
}

__global__ __launch_bounds__(256) void make_dinv(const int* __restrict__ cnt,
                                                 float* __restrict__ dinv) {
    int v = blockIdx.x * blockDim.x + threadIdx.x;
    if (v < N_NODES) dinv[v] = rsqrtf((float)cnt[v] + 1.0f);  // +1 self-loop
}

// ---------------- GEMM (MFMA): msg = dinv[row]*(h@W), 32 rows/block (r9) ----------------
__global__ __launch_bounds__(256) void gemm_scale(
    const void* hsrc, int kind, int b_bf16,
    const unsigned short* __restrict__ Wt,
    const float* __restrict__ dinv,
    const float* __restrict__ mode,
    const float* __restrict__ alpha, const float* __restrict__ delta,
    unsigned short* A, float* __restrict__ B, int write_b) {
    const int wave = threadIdx.x >> 6;
    const int lane = threadIdx.x & 63;
    const int quad = lane >> 4;
    const int nidx = lane & 15;
    const int row0 = blockIdx.x * 32;
    const bool mf = mode[0] > 0.5f;

    short8 bfrag[2][4];
    #pragma unroll
    for (int half = 0; half < 2; ++half) {
        int c = wave * 32 + half * 16 + nidx;
        #pragma unroll
        for (int kk = 0; kk < 4; ++kk)
            bfrag[half][kk] = *(const short8*)(Wt + (size_t)c * DIM + kk * 32 + quad * 8);
    }

    #pragma unroll
    for (int tile = 0; tile < 2; ++tile) {
        const int rt = row0 + tile * 16;
        if (rt >= N_NODES) break;               // block-uniform guard

        short8 afrag[4];
        if (kind == 0) {
            if (mf) {
                const float* xf = (const float*)hsrc;
                #pragma unroll
                for (int kk = 0; kk < 4; ++kk) {
                    const float4v* xr = (const float4v*)(xf + (size_t)(rt + nidx) * DIM + kk * 32 + quad * 8);
                    float4v p0 = xr[0], p1 = xr[1];
                    #pragma unroll
                    for (int j = 0; j < 4; ++j) {
                        afrag[kk][j]     = (short)f32_to_bf16_bits(p0[j]);
                        afrag[kk][4 + j] = (short)f32_to_bf16_bits(p1[j]);
                    }
                }
            } else {
                const unsigned short* hu = (const unsigned short*)hsrc;
                #pragma unroll
                for (int kk = 0; kk < 4; ++kk)
                    afrag[kk] = *(const short8*)(hu + (size_t)(rt + nidx) * DIM + kk * 32 + quad * 8);
            }
        } else if (b_bf16) {
            const unsigned short* Bh = (const unsigned short*)hsrc;
            const float dv = dinv[rt + nidx];
            #pragma unroll
            for (int kk = 0; kk < 4; ++kk) {
                short8 braw = *(const short8*)(Bh + (size_t)(rt + nidx) * DIM + kk * 32 + quad * 8);
                const float* ap = alpha + kk * 32 + quad * 8;
                const float* dp = delta + kk * 32 + quad * 8;
                float4v A0 = *(const float4v*)ap, A1 = *(const float4v*)(ap + 4);
                float4v D0 = *(const float4v*)dp, D1 = *(const float4v*)(dp + 4);
                #pragma unroll
                for (int j = 0; j < 4; ++j) {
                    float v0 = bf16_bits_to_f32((unsigned short)braw[j]);
                    float v1 = bf16_bits_to_f32((unsigned short)braw[4 + j]);
                    float h0 = fmaxf(fmaf(A0[j] * dv, v0, D0[j]), 0.f);
                    float h1 = fmaxf(fmaf(A1[j] * dv, v1, D1[j]), 0.f);
                    afrag[kk][j]     = (short)f32_to_bf16_bits(h0);
                    afrag[kk][4 + j] = (short)f32_to_bf16_bits(h1);
                }
            }
        } else {
            const float* Bf = (const float*)hsrc;
            const float dv = dinv[rt + nidx];
            #pragma unroll
            for (int kk = 0; kk < 4; ++kk) {
                const float* bp = Bf + (size_t)(rt + nidx) * DIM + kk * 32 + quad * 8;
                float4v p0 = *(const float4v*)bp;
                float4v p1 = *(const float4v*)(bp + 4);
                const float* ap = alpha + kk * 32 + quad * 8;
                const float* dp = delta + kk * 32 + quad * 8;
                float4v A0 = *(const float4v*)ap, A1 = *(const float4v*)(ap + 4);
                float4v D0 = *(const float4v*)dp, D1 = *(const float4v*)(dp + 4);
                #pragma unroll
                for (int j = 0; j < 4; ++j) {
                    float h0 = fmaxf(fmaf(A0[j] * dv, p0[j], D0[j]), 0.f);
                    float h1 = fmaxf(fmaf(A1[j] * dv, p1[j], D1[j]), 0.f);
                    afrag[kk][j]     = (short)f32_to_bf16_bits(h0);
                    afrag[kk][4 + j] = (short)f32_to_bf16_bits(h1);
                }
            }
        }

        float4v acc0 = {0.f, 0.f, 0.f, 0.f};
        float4v acc1 = {0.f, 0.f, 0.f, 0.f};
        #pragma unroll
        for (int kk = 0; kk < 4; ++kk) {
            acc0 = __builtin_amdgcn_mfma_f32_16x16x32_bf16(afrag[kk], bfrag[0][kk], acc0, 0, 0, 0);
            acc1 = __builtin_amdgcn_mfma_f32_16x16x32_bf16(afrag[kk], bfrag[1][kk], acc1, 0, 0, 0);
        }

        #pragma unroll
        for (int r = 0; r < 4; ++r) {
            int row = rt + quad * 4 + r;
            float d = dinv[row];
            float v0 = acc0[r] * d;
            float v1 = acc1[r] * d;
            size_t i0 = (size_t)row * DIM + wave * 32 + nidx;
            size_t i1 = i0 + 16;
            A[i0] = f32_to_bf16_bits(v0);
            A[i1] = f32_to_bf16_bits(v1);
            if (write_b) { B[i0] = v0; B[i1] = v1; }
        }
    }
}

// ---------------- padded-CSR gather v3.1 + fused BN stats (NO device fences here!) ----------------
// 1 node/wave, 16 lanes/edge x 16B: one wave-inst loads 4 full edge-rows. Chunk 0 is
// UNGUARDED (cv=0,w=0 padding makes OOB loads safe: row 0, weight 0 — valid even for
// deg=0); chunks 1,2 guarded by wave-uniform deg (divergence-free).
#define FMA8(vv, ww) do { \
    a0 = fmaf(ww, bf16_lo(vv.x), a0); a1 = fmaf(ww, bf16_hi(vv.x), a1); \
    a2 = fmaf(ww, bf16_lo(vv.y), a2); a3 = fmaf(ww, bf16_hi(vv.y), a3); \
    a4 = fmaf(ww, bf16_lo(vv.z), a4); a5 = fmaf(ww, bf16_hi(vv.z), a5); \
    a6 = fmaf(ww, bf16_lo(vv.w), a6); a7 = fmaf(ww, bf16_hi(vv.w), a7); } while (0)

#define CHUNK16(jbase) do { \
    int i0 = (jbase) + g, i1 = (jbase) + 4 + g, i2 = (jbase) + 8 + g, i3 = (jbase) + 12 + g; \
    int   s0 = __shfl(cv, i0);  float w0 = __shfl(wv, i0); \
    int   s1 = __shfl(cv, i1);  float w1 = __shfl(wv, i1); \
    int   s2 = __shfl(cv, i2);  float w2 = __shfl(wv, i2); \
    int   s3 = __shfl(cv, i3);  float w3 = __shfl(wv, i3); \
    uint4 v0 = *(const uint4*)(A + (size_t)s0 * DIM + c8); \
    uint4 v1 = *(const uint4*)(A + (size_t)s1 * DIM + c8); \
    uint4 v2 = *(const uint4*)(A + (size_t)s2 * DIM + c8); \
    uint4 v3 = *(const uint4*)(A + (size_t)s3 * DIM + c8); \
    FMA8(v0, w0); FMA8(v1, w1); FMA8(v2, w2); FMA8(v3, w3); } while (0)

template <int SC>
__global__ __launch_bounds__(256) void gather_csr(
    const int* __restrict__ cnt, const unsigned short* __restrict__ colu,
    const unsigned short* __restrict__ A,
    const float* __restrict__ dinv, const float* __restrict__ bias,
    unsigned short* __restrict__ Bh, float* __restrict__ partial) {
    __shared__ float sacc[4][128], sacc2[4][128];
    const int wave = threadIdx.x >> 6;
    const int lane = threadIdx.x & 63;
    const int g    = lane >> 4;        // edge slot within a 4-edge chunk
    const int c8   = (lane & 15) * 8;  // 8 columns (16B) per lane
    const int node = blockIdx.x * 4 + wave;   // exact: 12500*4 = 50000
    const int deg  = min(cnt[node], CAP);
    const int lo   = node * CAP;
    const float dv = dinv[node];

    // preload edge list + weights into per-lane registers (one coalesced pass)
    int   cv = (lane < deg) ? (int)colu[lo + lane] : 0;
    float wv = (lane < deg) ? (SC ? dinv[cv] : 1.0f) : 0.0f;

    // init accumulators with self-loop term (counted once via group 0)
    float a0, a1, a2, a3, a4, a5, a6, a7;
    {
        uint4 sv = *(const uint4*)(A + (size_t)node * DIM + c8);
        const float scl = (g == 0) ? (SC ? dv : 1.0f) : 0.0f;
        a0 = scl * bf16_lo(sv.x); a1 = scl * bf16_hi(sv.x);
        a2 = scl * bf16_lo(sv.y); a3 = scl * bf16_hi(sv.y);
        a4 = scl * bf16_lo(sv.z); a5 = scl * bf16_hi(sv.z);
        a6 = scl * bf16_lo(sv.w); a7 = scl * bf16_hi(sv.w);
    }

    CHUNK16(0);                       // unguarded: safe via zero-weight padding
    if (16 < deg) CHUNK16(16);        // wave-uniform guard
    if (32 < deg) CHUNK16(32);

    // reduce across the 4 edge-groups (lane bits 4,5)
    a0 += __shfl_xor(a0, 16); a0 += __shfl_xor(a0, 32);
    a1 += __shfl_xor(a1, 16); a1 += __shfl_xor(a1, 32);
    a2 += __shfl_xor(a2, 16); a2 += __shfl_xor(a2, 32);
    a3 += __shfl_xor(a3, 16); a3 += __shfl_xor(a3, 32);
    a4 += __shfl_xor(a4, 16); a4 += __shfl_xor(a4, 32);
    a5 += __shfl_xor(a5, 16); a5 += __shfl_xor(a5, 32);
    a6 += __shfl_xor(a6, 16); a6 += __shfl_xor(a6, 32);
    a7 += __shfl_xor(a7, 16); a7 += __shfl_xor(a7, 32);

    if (lane < 16) {
        unsigned int p0 = (unsigned int)f32_to_bf16_bits(a0) | ((unsigned int)f32_to_bf16_bits(a1) << 16);
        unsigned int p1 = (unsigned int)f32_to_bf16_bits(a2) | ((unsigned int)f32_to_bf16_bits(a3) << 16);
        unsigned int p2 = (unsigned int)f32_to_bf16_bits(a4) | ((unsigned int)f32_to_bf16_bits(a5) << 16);
        unsigned int p3 = (unsigned int)f32_to_bf16_bits(a6) | ((unsigned int)f32_to_bf16_bits(a7) << 16);
        uint4 st = {p0, p1, p2, p3};
        *(uint4*)(Bh + (size_t)node * DIM + c8) = st;
        float4 b0 = *(const float4*)(bias + c8);
        float4 b1 = *(const float4*)(bias + c8 + 4);
        float v0 = fmaf(dv, a0, b0.x), v1 = fmaf(dv, a1, b0.y);
        float v2 = fmaf(dv, a2, b0.z), v3 = fmaf(dv, a3, b0.w);
        float v4 = fmaf(dv, a4, b1.x), v5 = fmaf(dv, a5, b1.y);
        float v6 = fmaf(dv, a6, b1.z), v7 = fmaf(dv, a7, b1.w);
        sacc[wave][c8]     = v0;  sacc2[wave][c8]     = v0 * v0;
        sacc[wave][c8 + 1] = v1;  sacc2[wave][c8 + 1] = v1 * v1;
        sacc[wave][c8 + 2] = v2;  sacc2[wave][c8 + 2] = v2 * v2;
        sacc[wave][c8 + 3] = v3;  sacc2[wave][c8 + 3] = v3 * v3;
        sacc[wave][c8 + 4] = v4;  sacc2[wave][c8 + 4] = v4 * v4;
        sacc[wave][c8 + 5] = v5;  sacc2[wave][c8 + 5] = v5 * v5;
        sacc[wave][c8 + 6] = v6;  sacc2[wave][c8 + 6] = v6 * v6;
        sacc[wave][c8 + 7] = v7;  sacc2[wave][c8 + 7] = v7 * v7;
    }
    __syncthreads();
    const int t = threadIdx.x;
    float s;
    if (t < 128) s = sacc[0][t] + sacc[1][t] + sacc[2][t] + sacc[3][t];
    else { int c = t - 128; s = sacc2[0][c] + sacc2[1][c] + sacc2[2][c] + sacc2[3][c]; }
    partial[(size_t)blockIdx.x * 256 + t] = s;   // coalesced, no atomics
}

// ---------------- reduce partials -> stats, last block computes BN coefs ----------------
// Device fences are confined to this NARROW kernel (125 blocks) — cheap.
__global__ __launch_bounds__(256) void reduce_coefs(
    const float* __restrict__ partial, float* __restrict__ stats,
    int* __restrict__ done, const float* __restrict__ pf32, int l,
    float* __restrict__ alpha, float* __restrict__ delta) {
    const int t = threadIdx.x;
    const int rows = GATHER_BLOCKS / RED_BLOCKS;   // 100
    const int r0 = blockIdx.x * rows;
    float s = 0.f;
    for (int i = 0; i < rows; ++i)
        s += partial[(size_t)(r0 + i) * 256 + t];
    atomicAdd(&stats[t], s);
    __threadfence();
    __shared__ int lastFlag;
    if (t == 0) lastFlag = (atomicAdd(done, 1) == RED_BLOCKS - 1) ? 1 : 0;
    __syncthreads();
    if (lastFlag && t < 128) {
        float cs  = atomicAdd(&stats[t], 0.0f);
        float css = atomicAdd(&stats[t + 128], 0.0f);
        const float invN = 1.0f / N_NODES;
        float mu = cs * invN;
        float var = css * invN - mu * mu;
        float istd = rsqrtf(var + BN_EPS);
        float gg = pf32[384 + l * 128 + t];
        float bt = pf32[768 + l * 128 + t];
        float bi = pf32[l * 128 + t];
        float al = gg * istd;
        alpha[t] = al;
        delta[t] = al * (bi - mu) + bt;
        atomicExch(&stats[t], 0.0f);
        atomicExch(&stats[t + 128], 0.0f);
        if (t == 0) atomicExch(done, 0);
    }
}

// ---------------- BN coefs (fallback path only) ----------------
__global__ __launch_bounds__(128) void bn_coefs(
    const float* __restrict__ pf32, int l,
    float* __restrict__ colsum, float* __restrict__ colsumsq,
    float* __restrict__ alpha, float* __restrict__ delta) {
    int c = threadIdx.x;
    const float invN = 1.0f / N_NODES;
    float mu = colsum[c] * invN;
    float var = colsumsq[c] * invN - mu * mu;
    float istd = rsqrtf(var + BN_EPS);
    float gg = pf32[384 + l * 128 + c];
    float bt = pf32[768 + l * 128 + c];
    float bi = pf32[l * 128 + c];
    float al = gg * istd;
    alpha[c] = al;
    delta[c] = al * (bi - mu) + bt;
    colsum[c] = 0.f;
    colsumsq[c] = 0.f;
}

// ---------------- fallback path (ws too small): hist + scatter + bn_reduce ----------------
__global__ __launch_bounds__(256) void hist_dst(const int* __restrict__ dst,
                                                int* __restrict__ cnt) {
    int e = blockIdx.x * blockDim.x + threadIdx.x;
    if (e < N_EDGES) atomicAdd(&cnt[dst[e]], 1);
}

__global__ __launch_bounds__(256) void scatter_edges(
    const int* __restrict__ src, const int* __restrict__ dst,
    const unsigned short* __restrict__ A, float* __restrict__ B) {
    int t = blockIdx.x * blockDim.x + threadIdx.x;
    int e = t >> 4;
    if (e >= N_EDGES) return;
    int f = (t & 15) * 8;
    int s = src[e], d = dst[e];
    short8 v = *(const short8*)(A + (size_t)s * DIM + f);
    float* bp = B + (size_t)d * DIM + f;
    #pragma unroll
    for (int j = 0; j < 8; ++j)
        atomicAdd(bp + j, bf16_bits_to_f32((unsigned short)v[j]));
}

__global__ __launch_bounds__(256) void bn_reduce(
    const float* __restrict__ B, const float* __restrict__ dinv,
    const float* __restrict__ bias,
    float* __restrict__ colsum, float* __restrict__ colsumsq) {
    int c = threadIdx.x & 127;
    int half = threadIdx.x >> 7;
    float bb = bias[c];
    float s = 0.f, s2 = 0.f;
    for (int row = blockIdx.x * 2 + half; row < N_NODES; row += gridDim.x * 2) {
        float v = dinv[row] * B[(size_t)row * DIM + c] + bb;
        s += v;
        s2 += v * v;
    }
    __shared__ float ls[128], ls2[128];
    if (half == 1) { ls[c] = s; ls2[c] = s2; }
    __syncthreads();
    if (half == 0) {
        atomicAdd(&colsum[c], s + ls[c]);
        atomicAdd(&colsumsq[c], s2 + ls2[c]);
    }
}

// ---------------- final output: BN apply + ReLU, 8 elems/thread (vectorized) ----------------
__global__ __launch_bounds__(256) void bn_apply(
    const void* __restrict__ Bv, int b_bf16,
    const float* __restrict__ dinv,
    const float* __restrict__ alpha, const float* __restrict__ delta,
    const float* __restrict__ mode, void* __restrict__ out) {
    int t = blockIdx.x * blockDim.x + threadIdx.x;   // one thread = 8 elems
    if (t >= N_NODES * DIM / 8) return;
    int row = t >> 4;              // 16 threads per row
    int c8  = (t & 15) * 8;
    float dv = dinv[row];
    float4 A0 = *(const float4*)(alpha + c8), A1 = *(const float4*)(alpha + c8 + 4);
    float4 D0 = *(const float4*)(delta + c8), D1 = *(const float4*)(delta + c8 + 4);
    float v[8];
    if (b_bf16) {
        uint4 bv = *(const uint4*)((const unsigned short*)Bv + (size_t)row * DIM + c8);
        v[0] = bf16_lo(bv.x); v[1] = bf16_hi(bv.x);
        v[2] = bf16_lo(bv.y); v[3] = bf16_hi(bv.y);
        v[4] = bf16_lo(bv.z); v[5] = bf16_hi(bv.z);
        v[6] = bf16_lo(bv.w); v[7] = bf16_hi(bv.w);
    } else {
        const float* bf = (const float*)Bv + (size_t)row * DIM + c8;
        #pragma unroll
        for (int j = 0; j < 8; ++j) v[j] = bf[j];
    }
    float al[8] = {A0.x, A0.y, A0.z, A0.w, A1.x, A1.y, A1.z, A1.w};
    float de[8] = {D0.x, D0.y, D0.z, D0.w, D1.x, D1.y, D1.z, D1.w};
    float r[8];
    #pragma unroll
    for (int j = 0; j < 8; ++j)
        r[j] = fmaxf(fmaf(al[j] * dv, v[j], de[j]), 0.f);
    if (mode[0] > 0.5f) {
        float4* op = (float4*)((float*)out + (size_t)row * DIM + c8);
        float4 o0 = {r[0], r[1], r[2], r[3]};
        float4 o1 = {r[4], r[5], r[6], r[7]};
        op[0] = o0; op[1] = o1;
    } else {
        unsigned int p0 = (unsigned int)f32_to_bf16_bits(r[0]) | ((unsigned int)f32_to_bf16_bits(r[1]) << 16);
        unsigned int p1 = (unsigned int)f32_to_bf16_bits(r[2]) | ((unsigned int)f32_to_bf16_bits(r[3]) << 16);
        unsigned int p2 = (unsigned int)f32_to_bf16_bits(r[4]) | ((unsigned int)f32_to_bf16_bits(r[5]) << 16);
        unsigned int p3 = (unsigned int)f32_to_bf16_bits(r[6]) | ((unsigned int)f32_to_bf16_bits(r[7]) << 16);
        uint4 st = {p0, p1, p2, p3};
        *(uint4*)((unsigned short*)out + (size_t)row * DIM + c8) = st;
    }
}

extern "C" void kernel_launch(void* const* d_in, const int* in_sizes, int n_in,
                              void* d_out, int out_size, void* d_ws, size_t ws_size,
                              hipStream_t stream) {
    const void* x  = d_in[0];
    const int*  ei = (const int*)d_in[1];
    const void* W  = d_in[2];
    const void* b  = d_in[3];
    const void* g  = d_in[4];
    const void* be = d_in[5];

    unsigned short* hA = (unsigned short*)d_out;  // bf16 message buffer

    char* ws = (char*)d_ws;
    size_t off = 0;
    auto alloc = [&](size_t bytes) {
        char* p = ws + off;
        off = (off + bytes + 255) & ~(size_t)255;
        return p;
    };
    float* dinv     = (float*)alloc((size_t)N_NODES * 4);
    float* B        = (float*)alloc((size_t)N_NODES * DIM * 4);  // f32 for fallback; CSR uses as bf16
    unsigned short* Wt = (unsigned short*)alloc((size_t)3 * DIM * DIM * 2);
    float* pf32     = (float*)alloc(3 * 3 * DIM * 4);
    float* stats    = (float*)alloc(256 * 4);   // colsum[0:128] || colsumsq[128:256]
    float* alphaB   = (float*)alloc(128 * 4);
    float* deltaB   = (float*)alloc(128 * 4);
    float* mode     = (float*)alloc(64 * 4);
    int*   done     = (int*)alloc(64 * 4);
    int*   cnt      = (int*)alloc((size_t)N_NODES * 4);
    unsigned short* colu = (unsigned short*)alloc((size_t)N_NODES * CAP * 2);  // 4.8MB
    float* partial  = (float*)alloc((size_t)GATHER_BLOCKS * 256 * 4);          // 12.8MB
    int*   qcnt     = (int*)alloc((size_t)NPARTS * QSTRIDE * 4);               // 50KB padded
    // queue aliases partial (used strictly before the first gather writes partial)
    unsigned int* queue = (unsigned int*)partial;   // NPARTS*QCAP2*4 = 4.0MB <= 12.8MB
    const bool csr_ok = (ws_size >= off) || (ws_size == 0);
    float* colsum = stats;
    float* colsumsq = stats + 128;
    unsigned short* Bh = (unsigned short*)B;

    const int* srcv = ei;            // edge_index[0]
    const int* dstv = ei + N_EDGES;  // edge_index[1]

    const int PREP_BLOCKS = (3 * DIM * DIM + 3 * 3 * DIM + 255) / 256;
    prep<<<PREP_BLOCKS, 256, 0, stream>>>(
        (const unsigned short*)x, W, b, g, be, mode, Wt, pf32, qcnt, stats, done);

    if (csr_ok) {
        // LDS counting binning (391 blocks, direct-write) || layer-0 GEMM (32-row)
        fused_a<<<BIN_BLOCKS + GEMM_BLOCKS, 256, 0, stream>>>(
            srcv, dstv, qcnt, queue, x, Wt, mode, hA);
        // phase B: per-part queues -> padded CSR + cnt + dinv
        csr_build<<<NPARTS, 256, 0, stream>>>(qcnt, queue, colu, cnt, dinv);

        for (int l = 0; l < 3; ++l) {
            if (l > 0)
                gemm_scale<<<GEMM_BLOCKS, 256, 0, stream>>>(
                    (const void*)B, 2, 1, Wt + (size_t)l * DIM * DIM, dinv, mode,
                    alphaB, deltaB, hA, B, 0);
            if (l == 0)
                gather_csr<1><<<GATHER_BLOCKS, 256, 0, stream>>>(
                    cnt, colu, hA, dinv, pf32 + l * 128, Bh, partial);
            else
                gather_csr<0><<<GATHER_BLOCKS, 256, 0, stream>>>(
                    cnt, colu, hA, dinv, pf32 + l * 128, Bh, partial);
            reduce_coefs<<<RED_BLOCKS, 256, 0, stream>>>(
                partial, stats, done, pf32, l, alphaB, deltaB);
            if (l == 2)
                bn_apply<<<(N_NODES * DIM / 8 + 255) / 256, 256, 0, stream>>>(
                    (const void*)B, 1, dinv, alphaB, deltaB, mode, d_out);
        }
    } else {
        // fallback: original scatter pipeline (all layers use dinv-scaled gemm)
        zero_int<<<(N_NODES + 255) / 256, 256, 0, stream>>>(cnt, N_NODES);
        hist_dst<<<(N_EDGES + 255) / 256, 256, 0, stream>>>(dstv, cnt);
        make_dinv<<<(N_NODES + 255) / 256, 256, 0, stream>>>(cnt, dinv);

        for (int l = 0; l < 3; ++l) {
            const void* hin = (l == 0) ? x : (const void*)B;
            gemm_scale<<<GEMM_BLOCKS, 256, 0, stream>>>(
                hin, (l == 0) ? 0 : 2, 0, Wt + (size_t)l * DIM * DIM, dinv, mode,
                alphaB, deltaB, hA, B, 1);
            scatter_edges<<<(N_EDGES * 16) / 256, 256, 0, stream>>>(srcv, dstv, hA, B);
            bn_reduce<<<256, 256, 0, stream>>>(B, dinv, pf32 + l * 128, colsum, colsumsq);
            bn_coefs<<<1, 128, 0, stream>>>(pf32, l, colsum, colsumsq, alphaB, deltaB);
            if (l == 2)
                bn_apply<<<(N_NODES * DIM / 8 + 255) / 256, 256, 0, stream>>>(
                    (const void*)B, 0, dinv, alphaB, deltaB, mode, d_out);
        }
    }
}